// Round 2
// baseline (7226.683 us; speedup 1.0000x reference)
//
#include <hip/hip_runtime.h>

// Problem constants
#define NB   64
#define LA   256
#define DD   512
#define NCLS 10
#define NREF 50
#define NNEG 100
#define MARGIN 10.0f
#define NITER 27

// ---- workspace layout (float offsets) ----
// NOTE: cross cost is now stored TRANSPOSED: [b][500][256] (t0-point major)
#define OFF_CX   ((size_t)0)
#define SZ_CX    ((size_t)64*500*256)
#define OFF_CAA  (OFF_CX + SZ_CX)                 // aa cost     [64][256][256] (symmetric)
#define SZ_CAA   ((size_t)64*256*256)
#define OFF_CNN  (OFF_CAA + SZ_CAA)               // nn cost     [64][100][100] (symmetric)
#define SZ_CNN   ((size_t)64*100*100)
#define OFF_CLN  (OFF_CNN + SZ_CNN)               // ln cost     [64][50][100]
#define SZ_CLN   ((size_t)64*50*100)
#define OFF_CGN  (OFF_CLN + SZ_CLN)               // gn cost     [64][50][100]
#define SZ_CGN   ((size_t)64*50*100)
#define OFF_CTT  (OFF_CGN + SZ_CGN)               // tt cost     [10][50][50] (symmetric)
#define SZ_CTT   ((size_t)10*50*50)
#define OFF_SQA  (OFF_CTT + SZ_CTT)
#define OFF_SQN  (OFF_SQA + (size_t)64*256)
#define OFF_SQT  (OFF_SQN + (size_t)64*100)
#define OFF_OTX  (OFF_SQT + (size_t)500)
#define OFF_OTAA (OFF_OTX + (size_t)640)
#define OFF_OTNN (OFF_OTAA + (size_t)64)
#define OFF_OTLN (OFF_OTNN + (size_t)64)
#define OFF_OTGN (OFF_OTLN + (size_t)64)
#define OFF_OTTT (OFF_OTGN + (size_t)64)

__device__ __forceinline__ float eps_at(int it) {
    return (it < 12) ? ldexpf(8.0f, -it) : 0.0025f;
}

__device__ __forceinline__ float block_sum256(float v, float* red, int tid) {
    #pragma unroll
    for (int off = 1; off < 64; off <<= 1) v += __shfl_xor(v, off);
    if ((tid & 63) == 0) red[tid >> 6] = v;
    __syncthreads();
    return red[0] + red[1] + red[2] + red[3];
}

// Chunked two-pass LSE core: returns  m + eps*ln( sum_r exp((u_r - m)/eps) )
// with u_r = pot[r] - Crow[r*STRIDE], m = max_r u_r.
// Exps are independent (4 accumulators), one rescale per 25-chunk.
template<int LEN, int STRIDE>
__device__ __forceinline__ float lse_val(const float* __restrict__ pot,
                                         const float* __restrict__ Crow,
                                         float eps, float ieps) {
    constexpr int CH = 25;
    constexpr int NCH = (LEN + CH - 1) / CH;
    float m = -3.4e38f, s = 0.f;
    #pragma unroll
    for (int ch = 0; ch < NCH; ++ch) {
        float up[CH];
        #pragma unroll
        for (int q = 0; q < CH; ++q) {
            int r = ch * CH + q;
            up[q] = (r < LEN) ? (pot[r] - Crow[(size_t)r * STRIDE]) : -3.4e38f;
        }
        float a0 = -3.4e38f, a1 = -3.4e38f, a2 = -3.4e38f, a3 = -3.4e38f;
        #pragma unroll
        for (int q = 0; q < CH; ++q) {
            if ((q & 3) == 0) a0 = fmaxf(a0, up[q]);
            else if ((q & 3) == 1) a1 = fmaxf(a1, up[q]);
            else if ((q & 3) == 2) a2 = fmaxf(a2, up[q]);
            else a3 = fmaxf(a3, up[q]);
        }
        float cm = fmaxf(fmaxf(a0, a1), fmaxf(a2, a3));
        float mn = fmaxf(m, cm);
        s *= __expf((m - mn) * ieps);
        float s0 = 0.f, s1 = 0.f, s2 = 0.f, s3 = 0.f;
        #pragma unroll
        for (int q = 0; q < CH; ++q) {
            float e = __expf((up[q] - mn) * ieps);
            if ((q & 3) == 0) s0 += e;
            else if ((q & 3) == 1) s1 += e;
            else if ((q & 3) == 2) s2 += e;
            else s3 += e;
        }
        s += (s0 + s1) + (s2 + s3);
        m = mn;
    }
    return m + eps * __logf(s);
}

// ---------------- K0: 0.5 * squared norms ----------------
__global__ __launch_bounds__(256) void sq_kernel(const float* __restrict__ anchor,
                                                 const float* __restrict__ neg,
                                                 const float* __restrict__ t0,
                                                 float* __restrict__ ws) {
    int gw   = (blockIdx.x * 256 + threadIdx.x) >> 6;
    int lane = threadIdx.x & 63;
    const int nA = NB * LA, nN = NB * NNEG, nT = NCLS * NREF;
    if (gw >= nA + nN + nT) return;
    const float* row; float* outp;
    if (gw < nA)           { row = anchor + (size_t)gw * DD;          outp = ws + OFF_SQA + gw; }
    else if (gw < nA + nN) { int r = gw - nA;      row = neg + (size_t)r * DD; outp = ws + OFF_SQN + r; }
    else                   { int r = gw - nA - nN; row = t0  + (size_t)r * DD; outp = ws + OFF_SQT + r; }
    const float4* r4 = (const float4*)row;
    float4 u = r4[lane * 2], v = r4[lane * 2 + 1];
    float s = u.x*u.x + u.y*u.y + u.z*u.z + u.w*u.w
            + v.x*v.x + v.y*v.y + v.z*v.z + v.w*v.w;
    #pragma unroll
    for (int off = 1; off < 64; off <<= 1) s += __shfl_xor(s, off);
    if (lane == 0) *outp = 0.5f * s;
}

// ---------------- K1: cost matrices (cross written transposed) ----------------
#define TS 64
#define KC 16
__global__ __launch_bounds__(256) void cost_kernel(const float* __restrict__ anchor,
                                                   const float* __restrict__ neg,
                                                   const float* __restrict__ t0,
                                                   const int* __restrict__ gneg,
                                                   float* __restrict__ ws) {
    __shared__ __align__(16) float As[KC][TS];
    __shared__ __align__(16) float Bs[KC][TS];
    int bid = blockIdx.x, tid = threadIdx.x;
    const float *X, *Y, *sqx, *sqy;
    float* Cout; int N, M, ldc, r0, c0;
    bool tr = false;
    if (bid < 2048) {                     // cross: anchor[b] x t0_flat (256 x 500) -> store [m][n]
        int b = bid >> 5, t = bid & 31; r0 = (t >> 3) * 64; c0 = (t & 7) * 64;
        X = anchor + (size_t)b * LA * DD; Y = t0; N = LA; M = 500; ldc = 500;
        Cout = ws + OFF_CX + (size_t)b * 500 * 256;
        sqx = ws + OFF_SQA + b * LA; sqy = ws + OFF_SQT;
        tr = true;
    } else if (bid < 3072) {              // aa
        int b2 = bid - 2048; int b = b2 >> 4, t = b2 & 15; r0 = (t >> 2) * 64; c0 = (t & 3) * 64;
        X = Y = anchor + (size_t)b * LA * DD; N = M = LA; ldc = LA;
        Cout = ws + OFF_CAA + (size_t)b * LA * LA;
        sqx = sqy = ws + OFF_SQA + b * LA;
    } else if (bid < 3328) {              // nn
        int b2 = bid - 3072; int b = b2 >> 2, t = b2 & 3; r0 = (t >> 1) * 64; c0 = (t & 1) * 64;
        X = Y = neg + (size_t)b * NNEG * DD; N = M = NNEG; ldc = NNEG;
        Cout = ws + OFF_CNN + (size_t)b * NNEG * NNEG;
        sqx = sqy = ws + OFF_SQN + b * NNEG;
    } else if (bid < 3456) {              // ln
        int b2 = bid - 3328; int b = b2 >> 1; r0 = 0; c0 = (b2 & 1) * 64;
        X = t0 + (size_t)9 * NREF * DD; Y = neg + (size_t)b * NNEG * DD;
        N = NREF; M = NNEG; ldc = NNEG;
        Cout = ws + OFF_CLN + (size_t)b * NREF * NNEG;
        sqx = ws + OFF_SQT + 9 * NREF; sqy = ws + OFF_SQN + b * NNEG;
    } else if (bid < 3584) {              // gn
        int b2 = bid - 3456; int b = b2 >> 1; r0 = 0; c0 = (b2 & 1) * 64;
        int gc = gneg[b];
        X = t0 + (size_t)gc * NREF * DD; Y = neg + (size_t)b * NNEG * DD;
        N = NREF; M = NNEG; ldc = NNEG;
        Cout = ws + OFF_CGN + (size_t)b * NREF * NNEG;
        sqx = ws + OFF_SQT + gc * NREF; sqy = ws + OFF_SQN + b * NNEG;
    } else {                              // tt
        int c = bid - 3584; r0 = 0; c0 = 0;
        X = Y = t0 + (size_t)c * NREF * DD; N = M = NREF; ldc = NREF;
        Cout = ws + OFF_CTT + (size_t)c * NREF * NREF;
        sqx = sqy = ws + OFF_SQT + c * NREF;
    }
    int lr = tid >> 2, lk = (tid & 3) << 2;
    int tx = tid & 15, ty = tid >> 4;
    bool xok = (r0 + lr) < N, yok = (c0 + lr) < M;
    const float* xrow = X + (size_t)(r0 + lr) * DD;
    const float* yrow = Y + (size_t)(c0 + lr) * DD;
    float acc[4][4];
    #pragma unroll
    for (int a = 0; a < 4; a++)
        #pragma unroll
        for (int b = 0; b < 4; b++) acc[a][b] = 0.f;
    for (int k0 = 0; k0 < DD; k0 += KC) {
        float4 xa = xok ? *(const float4*)(xrow + k0 + lk) : make_float4(0,0,0,0);
        float4 ya = yok ? *(const float4*)(yrow + k0 + lk) : make_float4(0,0,0,0);
        __syncthreads();
        As[lk+0][lr]=xa.x; As[lk+1][lr]=xa.y; As[lk+2][lr]=xa.z; As[lk+3][lr]=xa.w;
        Bs[lk+0][lr]=ya.x; Bs[lk+1][lr]=ya.y; Bs[lk+2][lr]=ya.z; Bs[lk+3][lr]=ya.w;
        __syncthreads();
        #pragma unroll
        for (int k = 0; k < KC; k++) {
            const float4 av = *(const float4*)&As[k][ty << 2];
            const float4 bv = *(const float4*)&Bs[k][tx << 2];
            acc[0][0]=fmaf(av.x,bv.x,acc[0][0]); acc[0][1]=fmaf(av.x,bv.y,acc[0][1]);
            acc[0][2]=fmaf(av.x,bv.z,acc[0][2]); acc[0][3]=fmaf(av.x,bv.w,acc[0][3]);
            acc[1][0]=fmaf(av.y,bv.x,acc[1][0]); acc[1][1]=fmaf(av.y,bv.y,acc[1][1]);
            acc[1][2]=fmaf(av.y,bv.z,acc[1][2]); acc[1][3]=fmaf(av.y,bv.w,acc[1][3]);
            acc[2][0]=fmaf(av.z,bv.x,acc[2][0]); acc[2][1]=fmaf(av.z,bv.y,acc[2][1]);
            acc[2][2]=fmaf(av.z,bv.z,acc[2][2]); acc[2][3]=fmaf(av.z,bv.w,acc[2][3]);
            acc[3][0]=fmaf(av.w,bv.x,acc[3][0]); acc[3][1]=fmaf(av.w,bv.y,acc[3][1]);
            acc[3][2]=fmaf(av.w,bv.z,acc[3][2]); acc[3][3]=fmaf(av.w,bv.w,acc[3][3]);
        }
    }
    #pragma unroll
    for (int a = 0; a < 4; a++) {
        int n = r0 + (ty << 2) + a;
        if (n < N) {
            float sx = sqx[n];
            #pragma unroll
            for (int b = 0; b < 4; b++) {
                int m = c0 + (tx << 2) + b;
                if (m < M) {
                    float v = sx + sqy[m] - acc[a][b];
                    if (tr) Cout[(size_t)m * 256 + n] = v;
                    else    Cout[(size_t)n * ldc + m] = v;
                }
            }
        }
    }
}

// ---------------- merged Sinkhorn: aa (64) + cross (640) + nn (64) + ln (64) + gn (64) + tt (10)
#define SMEMF 13328
#define LB50  (-3.9120230054f)   // log(1/50)

template<int N, int M, bool SYM>
__device__ void small_sink(const float* __restrict__ Cglob, float* __restrict__ smem,
                           float* __restrict__ red, int tid, float* __restrict__ outp) {
    constexpr int Mp = M + 1, Np = N + 1;
    float* Cs  = smem;                       // [N][Mp]
    float* CsT = smem + N * Mp;              // [M][Np], only if !SYM
    float* fS  = smem + 10496;               // [N<=128]
    float* gS  = smem + 10624;               // [M<=128]
    for (int e = tid; e < N * M; e += 256) {
        int n = e / M, mm = e - n * M;
        Cs[n * Mp + mm] = Cglob[e];
    }
    __syncthreads();
    if (!SYM) {
        for (int e = tid; e < N * M; e += 256) {
            int n = e / M, mm = e - n * M;
            CsT[mm * Np + n] = Cs[n * Mp + mm];
        }
    }
    if (tid < M) gS[tid] = 0.f;
    __syncthreads();
    constexpr float lac = (N == 100) ? -4.6051701860f : -3.9120230054f;
    constexpr float lbc = (M == 100) ? -4.6051701860f : -3.9120230054f;
    for (int it = 0; it < NITER; ++it) {
        float eps = eps_at(it), ieps = 1.0f / eps;
        if (tid < N) {
            float L = lse_val<M, 1>(gS, &Cs[tid * Mp], eps, ieps);
            fS[tid] = -fmaf(eps, lbc, L);
        }
        __syncthreads();
        if (tid < M) {
            float L = SYM ? lse_val<N, 1>(fS, &Cs[tid * Mp], eps, ieps)
                          : lse_val<N, 1>(fS, &CsT[tid * Np], eps, ieps);
            gS[tid] = -fmaf(eps, lac, L);
        }
        __syncthreads();
    }
    float contrib = 0.f;
    if (tid < N) contrib += fS[tid] * (1.0f / N);
    if (tid < M) contrib += gS[tid] * (1.0f / M);
    contrib = block_sum256(contrib, red, tid);
    if (tid == 0) *outp = contrib;
}

__global__ __launch_bounds__(256, 3) void sink_all(const float* __restrict__ weight,
                                                   float* __restrict__ ws) {
    __shared__ float smem[SMEMF];
    float* red = smem + 13320;
    int bid = blockIdx.x, tid = threadIdx.x;

    if (bid < 64) {
        // ---- aa: thread t owns output row t; symmetric C -> coalesced column reads ----
        int i = bid;
        float* ah = smem;                                    // [256] = eps*la + h
        const float* Cg = ws + OFF_CAA + (size_t)i * (LA * LA);
        float w = weight[(size_t)i * LA + tid];
        float la_r = (w > 0.f) ? __logf(fmaxf(w, 1e-30f)) : -1e9f;
        float h_r = 0.f, fs_r = 0.f;
        for (int app = 0; app < 54; ++app) {
            float eps = eps_at(app >> 1), ieps = 1.0f / eps;
            ah[tid] = fmaf(eps, la_r, h_r);
            __syncthreads();
            float L = lse_val<LA, LA>(ah, Cg + tid, eps, ieps);
            h_r = -L;
            if (app == 52) fs_r = h_r;
            __syncthreads();
        }
        float c = w * (fs_r + h_r);
        c = block_sum256(c, red, tid);
        if (tid == 0) ws[OFF_OTAA + i] = c;

    } else if (bid < 704) {
        // ---- cross: C^T in LDS [50][260]; thread-per-output f; 16-lane-group g ----
        int ii = bid - 64;
        int i = ii / 10, c = ii - i * 10;
        float* CsT = smem;                 // [50][260]
        float* agS = smem + 13000;         // [256] = eps*la + f
        float* gS  = smem + 13256;         // [64]
        const float* Cgbase = ws + OFF_CX + (size_t)i * (500 * 256) + (size_t)c * (50 * 256);
        for (int e = tid; e < 3200; e += 256) {
            int r = e >> 6, n4 = (e & 63) << 2;
            *(float4*)&CsT[r * 260 + n4] = *(const float4*)&Cgbase[(size_t)e << 2];
        }
        float w = weight[(size_t)i * LA + tid];
        float la_r = (w > 0.f) ? __logf(fmaxf(w, 1e-30f)) : -1e9f;
        if (tid < 64) gS[tid] = 0.f;
        __syncthreads();
        int grp = tid >> 4, j = tid & 15;
        for (int it = 0; it < NITER; ++it) {
            float eps = eps_at(it), ieps = 1.0f / eps;
            // f-update: output n = tid, reduce over r=0..49 (conflict-free column reads)
            {
                float L = lse_val<50, 260>(gS, &CsT[tid], eps, ieps);
                float f = -fmaf(eps, LB50, L);
                agS[tid] = fmaf(eps, la_r, f);
            }
            __syncthreads();
            // g-update: 16-lane groups, output o, reduce over n=0..255
            for (int o = grp; o < 50; o += 16) {
                const float* Cr = &CsT[o * 260];
                float up[16];
                #pragma unroll
                for (int k = 0; k < 16; ++k) up[k] = agS[j + (k << 4)] - Cr[j + (k << 4)];
                float a0 = up[0], a1 = up[1], a2 = up[2], a3 = up[3];
                #pragma unroll
                for (int k = 4; k < 16; ++k) {
                    if ((k & 3) == 0) a0 = fmaxf(a0, up[k]);
                    else if ((k & 3) == 1) a1 = fmaxf(a1, up[k]);
                    else if ((k & 3) == 2) a2 = fmaxf(a2, up[k]);
                    else a3 = fmaxf(a3, up[k]);
                }
                float m = fmaxf(fmaxf(a0, a1), fmaxf(a2, a3));
                #pragma unroll
                for (int off = 1; off < 16; off <<= 1) m = fmaxf(m, __shfl_xor(m, off));
                float s0 = 0.f, s1 = 0.f, s2 = 0.f, s3 = 0.f;
                #pragma unroll
                for (int k = 0; k < 16; ++k) {
                    float e = __expf((up[k] - m) * ieps);
                    if ((k & 3) == 0) s0 += e;
                    else if ((k & 3) == 1) s1 += e;
                    else if ((k & 3) == 2) s2 += e;
                    else s3 += e;
                }
                float s = (s0 + s1) + (s2 + s3);
                #pragma unroll
                for (int off = 1; off < 16; off <<= 1) s += __shfl_xor(s, off);
                if (j == 0) gS[o] = -(m + eps * __logf(s));
            }
            __syncthreads();
        }
        float f_t = agS[tid] - 0.0025f * la_r;
        float contrib = w * f_t + (tid < 50 ? 0.02f * gS[tid] : 0.f);
        contrib = block_sum256(contrib, red, tid);
        if (tid == 0) ws[OFF_OTX + ii] = contrib;

    } else if (bid < 768) {
        int q = bid - 704;
        small_sink<100, 100, true>(ws + OFF_CNN + (size_t)q * 10000, smem, red, tid,
                                   ws + OFF_OTNN + q);
    } else if (bid < 896) {
        int q = bid - 768;
        const float* base = (q < 64) ? (ws + OFF_CLN + (size_t)q * 5000)
                                     : (ws + OFF_CGN + (size_t)(q - 64) * 5000);
        float* outp = (q < 64) ? (ws + OFF_OTLN + q) : (ws + OFF_OTGN + (q - 64));
        small_sink<50, 100, false>(base, smem, red, tid, outp);
    } else {
        int q = bid - 896;
        small_sink<50, 50, true>(ws + OFF_CTT + (size_t)q * 2500, smem, red, tid,
                                 ws + OFF_OTTT + q);
    }
}

// ---------------- K3: final loss assembly ----------------
__global__ void assemble_kernel(const int* __restrict__ grade, const int* __restrict__ gneg,
                                const float* __restrict__ ws, float* __restrict__ out) {
    int i = threadIdx.x;
    float total = 0.f;
    if (i < 64) {
        float aa  = ws[OFF_OTAA + i];
        float nn  = ws[OFF_OTNN + i];
        float lnv = ws[OFF_OTLN + i];
        float gnv = ws[OFF_OTGN + i];
        int g  = grade[i];
        int gi = gneg[i];
        float tt9 = ws[OFF_OTTT + 9];
        float ttg = ws[OFF_OTTT + gi];
        float Slast = lnv - 0.5f * tt9 - 0.5f * nn;
        float Sgn   = gnv - 0.5f * ttg - 0.5f * nn;
        float Sv[10];
        #pragma unroll
        for (int k = 0; k < 10; k++)
            Sv[k] = ws[OFF_OTX + i * 10 + k] - 0.5f * aa - 0.5f * ws[OFF_OTTT + k];
        float pos = 0.f;
        #pragma unroll
        for (int k = 0; k < 10; k++) pos = (k == g) ? Sv[k] : pos;
        float hc = 0.f;
        #pragma unroll
        for (int k = 0; k < 10; k++)
            if (k != g) hc += fmaxf(pos - Sv[k] + MARGIN, 0.f);
        float hn = fmaxf(pos - Slast + MARGIN, 0.f);
        total = hc + hn + fabsf(Sgn - Slast);
    }
    #pragma unroll
    for (int off = 1; off < 64; off <<= 1) total += __shfl_xor(total, off);
    if (i == 0) out[0] = total * (1.0f / 64.0f);
}

extern "C" void kernel_launch(void* const* d_in, const int* in_sizes, int n_in,
                              void* d_out, int out_size, void* d_ws, size_t ws_size,
                              hipStream_t stream) {
    const float* anchor = (const float*)d_in[0];
    const int*   grade  = (const int*)d_in[2];
    const float* weight = (const float*)d_in[3];
    const float* neg    = (const float*)d_in[4];
    const int*   gneg   = (const int*)d_in[5];
    const float* t0     = (const float*)d_in[6];
    float* ws  = (float*)d_ws;
    float* out = (float*)d_out;

    sq_kernel      <<<5821, 256, 0, stream>>>(anchor, neg, t0, ws);
    cost_kernel    <<<3594, 256, 0, stream>>>(anchor, neg, t0, gneg, ws);
    sink_all       <<<906, 256, 0, stream>>>(weight, ws);
    assemble_kernel<<<1, 64, 0, stream>>>(grade, gneg, ws, out);
}

// Round 3
// 985.045 us; speedup vs baseline: 7.3364x; 7.3364x over previous
//
#include <hip/hip_runtime.h>

// Problem constants
#define NB   64
#define LA   256
#define DD   512
#define NCLS 10
#define NREF 50
#define NNEG 100
#define MARGIN 10.0f
#define NITER 27

#define LOG2E 1.44269504f
#define LN2   0.69314718f

// ---- workspace layout (float offsets) ----
// cross cost stored TRANSPOSED: [b][500][256] (t0-point major)
#define OFF_CX   ((size_t)0)
#define SZ_CX    ((size_t)64*500*256)
#define OFF_CAA  (OFF_CX + SZ_CX)                 // aa cost     [64][256][256] (symmetric)
#define SZ_CAA   ((size_t)64*256*256)
#define OFF_CNN  (OFF_CAA + SZ_CAA)               // nn cost     [64][100][100] (symmetric)
#define SZ_CNN   ((size_t)64*100*100)
#define OFF_CLN  (OFF_CNN + SZ_CNN)               // ln cost     [64][50][100]
#define SZ_CLN   ((size_t)64*50*100)
#define OFF_CGN  (OFF_CLN + SZ_CLN)               // gn cost     [64][50][100]
#define SZ_CGN   ((size_t)64*50*100)
#define OFF_CTT  (OFF_CGN + SZ_CGN)               // tt cost     [10][50][50] (symmetric)
#define SZ_CTT   ((size_t)10*50*50)
#define OFF_SQA  (OFF_CTT + SZ_CTT)
#define OFF_SQN  (OFF_SQA + (size_t)64*256)
#define OFF_SQT  (OFF_SQN + (size_t)64*100)
#define OFF_OTX  (OFF_SQT + (size_t)500)
#define OFF_OTAA (OFF_OTX + (size_t)640)
#define OFF_OTNN (OFF_OTAA + (size_t)64)
#define OFF_OTLN (OFF_OTNN + (size_t)64)
#define OFF_OTGN (OFF_OTLN + (size_t)64)
#define OFF_OTTT (OFF_OTGN + (size_t)64)

__device__ __forceinline__ float eps_at(int it) {
    return (it < 12) ? ldexpf(8.0f, -it) : 0.0025f;
}

__device__ __forceinline__ float block_sum256(float v, float* red, int tid) {
    #pragma unroll
    for (int off = 1; off < 64; off <<= 1) v += __shfl_xor(v, off);
    if ((tid & 63) == 0) red[tid >> 6] = v;
    __syncthreads();
    return red[0] + red[1] + red[2] + red[3];
}

// Two-pass LSE over LDS-resident data, no register arrays (spill-proof):
// returns m + eps*ln( sum_r exp((pot[r]-Crow[r*STRIDE] - m)/eps) ), m = max.
template<int LEN, int STRIDE>
__device__ __forceinline__ float lse_val(const float* __restrict__ pot,
                                         const float* __restrict__ Crow,
                                         float eps, float ieps) {
    float m0 = -3.4e38f, m1 = -3.4e38f, m2 = -3.4e38f, m3 = -3.4e38f;
    #pragma unroll
    for (int r = 0; r < LEN; ++r) {
        float u = pot[r] - Crow[(size_t)r * STRIDE];
        if ((r & 3) == 0) m0 = fmaxf(m0, u);
        else if ((r & 3) == 1) m1 = fmaxf(m1, u);
        else if ((r & 3) == 2) m2 = fmaxf(m2, u);
        else m3 = fmaxf(m3, u);
    }
    float m = fmaxf(fmaxf(m0, m1), fmaxf(m2, m3));
    float ie2 = ieps * LOG2E;
    float s0 = 0.f, s1 = 0.f, s2 = 0.f, s3 = 0.f;
    #pragma unroll
    for (int r = 0; r < LEN; ++r) {
        float e = exp2f((pot[r] - Crow[(size_t)r * STRIDE] - m) * ie2);
        if ((r & 3) == 0) s0 += e;
        else if ((r & 3) == 1) s1 += e;
        else if ((r & 3) == 2) s2 += e;
        else s3 += e;
    }
    float s = (s0 + s1) + (s2 + s3);
    return fmaf(eps * LN2, __log2f(s), m);
}

// ---------------- K0: 0.5 * squared norms ----------------
__global__ __launch_bounds__(256) void sq_kernel(const float* __restrict__ anchor,
                                                 const float* __restrict__ neg,
                                                 const float* __restrict__ t0,
                                                 float* __restrict__ ws) {
    int gw   = (blockIdx.x * 256 + threadIdx.x) >> 6;
    int lane = threadIdx.x & 63;
    const int nA = NB * LA, nN = NB * NNEG, nT = NCLS * NREF;
    if (gw >= nA + nN + nT) return;
    const float* row; float* outp;
    if (gw < nA)           { row = anchor + (size_t)gw * DD;          outp = ws + OFF_SQA + gw; }
    else if (gw < nA + nN) { int r = gw - nA;      row = neg + (size_t)r * DD; outp = ws + OFF_SQN + r; }
    else                   { int r = gw - nA - nN; row = t0  + (size_t)r * DD; outp = ws + OFF_SQT + r; }
    const float4* r4 = (const float4*)row;
    float4 u = r4[lane * 2], v = r4[lane * 2 + 1];
    float s = u.x*u.x + u.y*u.y + u.z*u.z + u.w*u.w
            + v.x*v.x + v.y*v.y + v.z*v.z + v.w*v.w;
    #pragma unroll
    for (int off = 1; off < 64; off <<= 1) s += __shfl_xor(s, off);
    if (lane == 0) *outp = 0.5f * s;
}

// ---------------- K1: cost matrices (cross written transposed) ----------------
#define TS 64
#define KC 16
__global__ __launch_bounds__(256) void cost_kernel(const float* __restrict__ anchor,
                                                   const float* __restrict__ neg,
                                                   const float* __restrict__ t0,
                                                   const int* __restrict__ gneg,
                                                   float* __restrict__ ws) {
    __shared__ __align__(16) float As[KC][TS];
    __shared__ __align__(16) float Bs[KC][TS];
    int bid = blockIdx.x, tid = threadIdx.x;
    const float *X, *Y, *sqx, *sqy;
    float* Cout; int N, M, ldc, r0, c0;
    bool tr = false;
    if (bid < 2048) {                     // cross: anchor[b] x t0_flat (256 x 500) -> store [m][n]
        int b = bid >> 5, t = bid & 31; r0 = (t >> 3) * 64; c0 = (t & 7) * 64;
        X = anchor + (size_t)b * LA * DD; Y = t0; N = LA; M = 500; ldc = 500;
        Cout = ws + OFF_CX + (size_t)b * 500 * 256;
        sqx = ws + OFF_SQA + b * LA; sqy = ws + OFF_SQT;
        tr = true;
    } else if (bid < 3072) {              // aa
        int b2 = bid - 2048; int b = b2 >> 4, t = b2 & 15; r0 = (t >> 2) * 64; c0 = (t & 3) * 64;
        X = Y = anchor + (size_t)b * LA * DD; N = M = LA; ldc = LA;
        Cout = ws + OFF_CAA + (size_t)b * LA * LA;
        sqx = sqy = ws + OFF_SQA + b * LA;
    } else if (bid < 3328) {              // nn
        int b2 = bid - 3072; int b = b2 >> 2, t = b2 & 3; r0 = (t >> 1) * 64; c0 = (t & 1) * 64;
        X = Y = neg + (size_t)b * NNEG * DD; N = M = NNEG; ldc = NNEG;
        Cout = ws + OFF_CNN + (size_t)b * NNEG * NNEG;
        sqx = sqy = ws + OFF_SQN + b * NNEG;
    } else if (bid < 3456) {              // ln
        int b2 = bid - 3328; int b = b2 >> 1; r0 = 0; c0 = (b2 & 1) * 64;
        X = t0 + (size_t)9 * NREF * DD; Y = neg + (size_t)b * NNEG * DD;
        N = NREF; M = NNEG; ldc = NNEG;
        Cout = ws + OFF_CLN + (size_t)b * NREF * NNEG;
        sqx = ws + OFF_SQT + 9 * NREF; sqy = ws + OFF_SQN + b * NNEG;
    } else if (bid < 3584) {              // gn
        int b2 = bid - 3456; int b = b2 >> 1; r0 = 0; c0 = (b2 & 1) * 64;
        int gc = gneg[b];
        X = t0 + (size_t)gc * NREF * DD; Y = neg + (size_t)b * NNEG * DD;
        N = NREF; M = NNEG; ldc = NNEG;
        Cout = ws + OFF_CGN + (size_t)b * NREF * NNEG;
        sqx = ws + OFF_SQT + gc * NREF; sqy = ws + OFF_SQN + b * NNEG;
    } else {                              // tt
        int c = bid - 3584; r0 = 0; c0 = 0;
        X = Y = t0 + (size_t)c * NREF * DD; N = M = NREF; ldc = NREF;
        Cout = ws + OFF_CTT + (size_t)c * NREF * NREF;
        sqx = sqy = ws + OFF_SQT + c * NREF;
    }
    int lr = tid >> 2, lk = (tid & 3) << 2;
    int tx = tid & 15, ty = tid >> 4;
    bool xok = (r0 + lr) < N, yok = (c0 + lr) < M;
    const float* xrow = X + (size_t)(r0 + lr) * DD;
    const float* yrow = Y + (size_t)(c0 + lr) * DD;
    float acc[4][4];
    #pragma unroll
    for (int a = 0; a < 4; a++)
        #pragma unroll
        for (int b = 0; b < 4; b++) acc[a][b] = 0.f;
    for (int k0 = 0; k0 < DD; k0 += KC) {
        float4 xa = xok ? *(const float4*)(xrow + k0 + lk) : make_float4(0,0,0,0);
        float4 ya = yok ? *(const float4*)(yrow + k0 + lk) : make_float4(0,0,0,0);
        __syncthreads();
        As[lk+0][lr]=xa.x; As[lk+1][lr]=xa.y; As[lk+2][lr]=xa.z; As[lk+3][lr]=xa.w;
        Bs[lk+0][lr]=ya.x; Bs[lk+1][lr]=ya.y; Bs[lk+2][lr]=ya.z; Bs[lk+3][lr]=ya.w;
        __syncthreads();
        #pragma unroll
        for (int k = 0; k < KC; k++) {
            const float4 av = *(const float4*)&As[k][ty << 2];
            const float4 bv = *(const float4*)&Bs[k][tx << 2];
            acc[0][0]=fmaf(av.x,bv.x,acc[0][0]); acc[0][1]=fmaf(av.x,bv.y,acc[0][1]);
            acc[0][2]=fmaf(av.x,bv.z,acc[0][2]); acc[0][3]=fmaf(av.x,bv.w,acc[0][3]);
            acc[1][0]=fmaf(av.y,bv.x,acc[1][0]); acc[1][1]=fmaf(av.y,bv.y,acc[1][1]);
            acc[1][2]=fmaf(av.y,bv.z,acc[1][2]); acc[1][3]=fmaf(av.y,bv.w,acc[1][3]);
            acc[2][0]=fmaf(av.z,bv.x,acc[2][0]); acc[2][1]=fmaf(av.z,bv.y,acc[2][1]);
            acc[2][2]=fmaf(av.z,bv.z,acc[2][2]); acc[2][3]=fmaf(av.z,bv.w,acc[2][3]);
            acc[3][0]=fmaf(av.w,bv.x,acc[3][0]); acc[3][1]=fmaf(av.w,bv.y,acc[3][1]);
            acc[3][2]=fmaf(av.w,bv.z,acc[3][2]); acc[3][3]=fmaf(av.w,bv.w,acc[3][3]);
        }
    }
    #pragma unroll
    for (int a = 0; a < 4; a++) {
        int n = r0 + (ty << 2) + a;
        if (n < N) {
            float sx = sqx[n];
            #pragma unroll
            for (int b = 0; b < 4; b++) {
                int m = c0 + (tx << 2) + b;
                if (m < M) {
                    float v = sx + sqy[m] - acc[a][b];
                    if (tr) Cout[(size_t)m * 256 + n] = v;
                    else    Cout[(size_t)n * ldc + m] = v;
                }
            }
        }
    }
}

// ---------------- merged Sinkhorn ----------------
#define SMEMF 13328
#define LB50  (-3.9120230054f)

template<int N, int M, bool SYM>
__device__ void small_sink(const float* __restrict__ Cglob, float* __restrict__ smem,
                           float* __restrict__ red, int tid, float* __restrict__ outp) {
    constexpr int Mp = M + 1, Np = N + 1;
    float* Cs  = smem;                       // [N][Mp]
    float* CsT = smem + N * Mp;              // [M][Np], only if !SYM
    float* fS  = smem + 10496;
    float* gS  = smem + 10624;
    for (int e = tid; e < N * M; e += 256) {
        int n = e / M, mm = e - n * M;
        Cs[n * Mp + mm] = Cglob[e];
    }
    __syncthreads();
    if (!SYM) {
        for (int e = tid; e < N * M; e += 256) {
            int n = e / M, mm = e - n * M;
            CsT[mm * Np + n] = Cs[n * Mp + mm];
        }
    }
    if (tid < M) gS[tid] = 0.f;
    __syncthreads();
    constexpr float lac = (N == 100) ? -4.6051701860f : -3.9120230054f;
    constexpr float lbc = (M == 100) ? -4.6051701860f : -3.9120230054f;
    for (int it = 0; it < NITER; ++it) {
        float eps = eps_at(it), ieps = 1.0f / eps;
        if (tid < N) {
            float L = lse_val<M, 1>(gS, &Cs[tid * Mp], eps, ieps);
            fS[tid] = -fmaf(eps, lbc, L);
        }
        __syncthreads();
        if (tid < M) {
            float L = SYM ? lse_val<N, 1>(fS, &Cs[tid * Mp], eps, ieps)
                          : lse_val<N, 1>(fS, &CsT[tid * Np], eps, ieps);
            gS[tid] = -fmaf(eps, lac, L);
        }
        __syncthreads();
    }
    float contrib = 0.f;
    if (tid < N) contrib += fS[tid] * (1.0f / N);
    if (tid < M) contrib += gS[tid] * (1.0f / M);
    contrib = block_sum256(contrib, red, tid);
    if (tid == 0) *outp = contrib;
}

__global__ __launch_bounds__(256, 3) void sink_all(const float* __restrict__ weight,
                                                   float* __restrict__ ws) {
    __shared__ float smem[SMEMF];
    float* red = smem + 13320;
    int bid = blockIdx.x, tid = threadIdx.x;

    if (bid < 64) {
        // ---- aa: thread-per-output-column, two-pass over global (L2-resident) C ----
        int i = bid;
        float* ah = smem;                    // [256]: eps*la + h
        const float* col = ws + OFF_CAA + (size_t)i * (LA * LA) + tid;
        float w = weight[(size_t)i * LA + tid];
        float la_r = (w > 0.f) ? __logf(fmaxf(w, 1e-30f)) : -1e9f;
        float h_r = 0.f, fs_r = 0.f;
        for (int app = 0; app < 54; ++app) {
            float eps = eps_at(app >> 1), ieps = 1.0f / eps;
            ah[tid] = fmaf(eps, la_r, h_r);
            __syncthreads();
            float m0 = -3.4e38f, m1 = -3.4e38f, m2 = -3.4e38f, m3 = -3.4e38f;
            for (int r = 0; r < 256; r += 8) {
                float u0 = ah[r+0] - col[(size_t)(r+0) << 8];
                float u1 = ah[r+1] - col[(size_t)(r+1) << 8];
                float u2 = ah[r+2] - col[(size_t)(r+2) << 8];
                float u3 = ah[r+3] - col[(size_t)(r+3) << 8];
                float u4 = ah[r+4] - col[(size_t)(r+4) << 8];
                float u5 = ah[r+5] - col[(size_t)(r+5) << 8];
                float u6 = ah[r+6] - col[(size_t)(r+6) << 8];
                float u7 = ah[r+7] - col[(size_t)(r+7) << 8];
                m0 = fmaxf(m0, fmaxf(u0, u4));
                m1 = fmaxf(m1, fmaxf(u1, u5));
                m2 = fmaxf(m2, fmaxf(u2, u6));
                m3 = fmaxf(m3, fmaxf(u3, u7));
            }
            float m = fmaxf(fmaxf(m0, m1), fmaxf(m2, m3));
            float ie2 = ieps * LOG2E;
            float s0 = 0.f, s1 = 0.f, s2 = 0.f, s3 = 0.f;
            for (int r = 0; r < 256; r += 8) {
                float u0 = ah[r+0] - col[(size_t)(r+0) << 8];
                float u1 = ah[r+1] - col[(size_t)(r+1) << 8];
                float u2 = ah[r+2] - col[(size_t)(r+2) << 8];
                float u3 = ah[r+3] - col[(size_t)(r+3) << 8];
                float u4 = ah[r+4] - col[(size_t)(r+4) << 8];
                float u5 = ah[r+5] - col[(size_t)(r+5) << 8];
                float u6 = ah[r+6] - col[(size_t)(r+6) << 8];
                float u7 = ah[r+7] - col[(size_t)(r+7) << 8];
                s0 += exp2f((u0 - m) * ie2) + exp2f((u4 - m) * ie2);
                s1 += exp2f((u1 - m) * ie2) + exp2f((u5 - m) * ie2);
                s2 += exp2f((u2 - m) * ie2) + exp2f((u6 - m) * ie2);
                s3 += exp2f((u3 - m) * ie2) + exp2f((u7 - m) * ie2);
            }
            float s = (s0 + s1) + (s2 + s3);
            h_r = -fmaf(eps * LN2, __log2f(s), m);
            if (app == 52) fs_r = h_r;
            __syncthreads();
        }
        float c = w * (fs_r + h_r);
        c = block_sum256(c, red, tid);
        if (tid == 0) ws[OFF_OTAA + i] = c;

    } else if (bid < 704) {
        // ---- cross: C^T in LDS [50][260]; thread-per-output f; 16-lane-group g ----
        int ii = bid - 64;
        int i = ii / 10, c = ii - i * 10;
        float* CsT = smem;                 // [50][260]
        float* agS = smem + 13000;         // [256] = eps*la + f
        float* gS  = smem + 13256;         // [64]
        const float* Cgbase = ws + OFF_CX + (size_t)i * (500 * 256) + (size_t)c * (50 * 256);
        for (int e = tid; e < 3200; e += 256) {
            int r = e >> 6, n4 = (e & 63) << 2;
            *(float4*)&CsT[r * 260 + n4] = *(const float4*)&Cgbase[(size_t)e << 2];
        }
        float w = weight[(size_t)i * LA + tid];
        float la_r = (w > 0.f) ? __logf(fmaxf(w, 1e-30f)) : -1e9f;
        if (tid < 64) gS[tid] = 0.f;
        __syncthreads();
        int grp = tid >> 4, j = tid & 15;
        for (int it = 0; it < NITER; ++it) {
            float eps = eps_at(it), ieps = 1.0f / eps;
            {
                float L = lse_val<50, 260>(gS, &CsT[tid], eps, ieps);
                float f = -fmaf(eps, LB50, L);
                agS[tid] = fmaf(eps, la_r, f);
            }
            __syncthreads();
            float ie2 = ieps * LOG2E;
            for (int o = grp; o < 50; o += 16) {
                const float* Cr = &CsT[o * 260];
                float up[16];
                #pragma unroll
                for (int k = 0; k < 16; ++k) up[k] = agS[j + (k << 4)] - Cr[j + (k << 4)];
                float a0 = up[0], a1 = up[1], a2 = up[2], a3 = up[3];
                #pragma unroll
                for (int k = 4; k < 16; ++k) {
                    if ((k & 3) == 0) a0 = fmaxf(a0, up[k]);
                    else if ((k & 3) == 1) a1 = fmaxf(a1, up[k]);
                    else if ((k & 3) == 2) a2 = fmaxf(a2, up[k]);
                    else a3 = fmaxf(a3, up[k]);
                }
                float m = fmaxf(fmaxf(a0, a1), fmaxf(a2, a3));
                #pragma unroll
                for (int off = 1; off < 16; off <<= 1) m = fmaxf(m, __shfl_xor(m, off));
                float s0 = 0.f, s1 = 0.f, s2 = 0.f, s3 = 0.f;
                #pragma unroll
                for (int k = 0; k < 16; ++k) {
                    float e = exp2f((up[k] - m) * ie2);
                    if ((k & 3) == 0) s0 += e;
                    else if ((k & 3) == 1) s1 += e;
                    else if ((k & 3) == 2) s2 += e;
                    else s3 += e;
                }
                float s = (s0 + s1) + (s2 + s3);
                #pragma unroll
                for (int off = 1; off < 16; off <<= 1) s += __shfl_xor(s, off);
                if (j == 0) gS[o] = -fmaf(eps * LN2, __log2f(s), m);
            }
            __syncthreads();
        }
        float f_t = agS[tid] - 0.0025f * la_r;
        float contrib = w * f_t + (tid < 50 ? 0.02f * gS[tid] : 0.f);
        contrib = block_sum256(contrib, red, tid);
        if (tid == 0) ws[OFF_OTX + ii] = contrib;

    } else if (bid < 768) {
        int q = bid - 704;
        small_sink<100, 100, true>(ws + OFF_CNN + (size_t)q * 10000, smem, red, tid,
                                   ws + OFF_OTNN + q);
    } else if (bid < 896) {
        int q = bid - 768;
        const float* base = (q < 64) ? (ws + OFF_CLN + (size_t)q * 5000)
                                     : (ws + OFF_CGN + (size_t)(q - 64) * 5000);
        float* outp = (q < 64) ? (ws + OFF_OTLN + q) : (ws + OFF_OTGN + (q - 64));
        small_sink<50, 100, false>(base, smem, red, tid, outp);
    } else {
        int q = bid - 896;
        small_sink<50, 50, true>(ws + OFF_CTT + (size_t)q * 2500, smem, red, tid,
                                 ws + OFF_OTTT + q);
    }
}

// ---------------- K3: final loss assembly ----------------
__global__ void assemble_kernel(const int* __restrict__ grade, const int* __restrict__ gneg,
                                const float* __restrict__ ws, float* __restrict__ out) {
    int i = threadIdx.x;
    float total = 0.f;
    if (i < 64) {
        float aa  = ws[OFF_OTAA + i];
        float nn  = ws[OFF_OTNN + i];
        float lnv = ws[OFF_OTLN + i];
        float gnv = ws[OFF_OTGN + i];
        int g  = grade[i];
        int gi = gneg[i];
        float tt9 = ws[OFF_OTTT + 9];
        float ttg = ws[OFF_OTTT + gi];
        float Slast = lnv - 0.5f * tt9 - 0.5f * nn;
        float Sgn   = gnv - 0.5f * ttg - 0.5f * nn;
        float Sv[10];
        #pragma unroll
        for (int k = 0; k < 10; k++)
            Sv[k] = ws[OFF_OTX + i * 10 + k] - 0.5f * aa - 0.5f * ws[OFF_OTTT + k];
        float pos = 0.f;
        #pragma unroll
        for (int k = 0; k < 10; k++) pos = (k == g) ? Sv[k] : pos;
        float hc = 0.f;
        #pragma unroll
        for (int k = 0; k < 10; k++)
            if (k != g) hc += fmaxf(pos - Sv[k] + MARGIN, 0.f);
        float hn = fmaxf(pos - Slast + MARGIN, 0.f);
        total = hc + hn + fabsf(Sgn - Slast);
    }
    #pragma unroll
    for (int off = 1; off < 64; off <<= 1) total += __shfl_xor(total, off);
    if (i == 0) out[0] = total * (1.0f / 64.0f);
}

extern "C" void kernel_launch(void* const* d_in, const int* in_sizes, int n_in,
                              void* d_out, int out_size, void* d_ws, size_t ws_size,
                              hipStream_t stream) {
    const float* anchor = (const float*)d_in[0];
    const int*   grade  = (const int*)d_in[2];
    const float* weight = (const float*)d_in[3];
    const float* neg    = (const float*)d_in[4];
    const int*   gneg   = (const int*)d_in[5];
    const float* t0     = (const float*)d_in[6];
    float* ws  = (float*)d_ws;
    float* out = (float*)d_out;

    sq_kernel      <<<5821, 256, 0, stream>>>(anchor, neg, t0, ws);
    cost_kernel    <<<3594, 256, 0, stream>>>(anchor, neg, t0, gneg, ws);
    sink_all       <<<906, 256, 0, stream>>>(weight, ws);
    assemble_kernel<<<1, 64, 0, stream>>>(grade, gneg, ws, out);
}

// Round 4
// 795.646 us; speedup vs baseline: 9.0828x; 1.2380x over previous
//
#include <hip/hip_runtime.h>

// Problem constants
#define NB   64
#define LA   256
#define DD   512
#define NCLS 10
#define NREF 50
#define NNEG 100
#define MARGIN 10.0f
#define NITER 27

#define LOG2E 1.44269504f
#define LN2   0.69314718f

// ---- workspace layout (float offsets) ----
// cross cost stored TRANSPOSED: [b][500][256] (t0-point major)
#define OFF_CX   ((size_t)0)
#define SZ_CX    ((size_t)64*500*256)
#define OFF_CAA  (OFF_CX + SZ_CX)                 // aa cost     [64][256][256] (symmetric)
#define SZ_CAA   ((size_t)64*256*256)
#define OFF_CNN  (OFF_CAA + SZ_CAA)               // nn cost     [64][100][100] (symmetric)
#define SZ_CNN   ((size_t)64*100*100)
#define OFF_CLN  (OFF_CNN + SZ_CNN)               // ln cost     [64][50][100]
#define SZ_CLN   ((size_t)64*50*100)
#define OFF_CGN  (OFF_CLN + SZ_CLN)               // gn cost     [64][50][100]
#define SZ_CGN   ((size_t)64*50*100)
#define OFF_CTT  (OFF_CGN + SZ_CGN)               // tt cost     [10][50][50] (symmetric)
#define SZ_CTT   ((size_t)10*50*50)
#define OFF_SQA  (OFF_CTT + SZ_CTT)
#define OFF_SQN  (OFF_SQA + (size_t)64*256)
#define OFF_SQT  (OFF_SQN + (size_t)64*100)
#define OFF_OTX  (OFF_SQT + (size_t)500)
#define OFF_OTAA (OFF_OTX + (size_t)640)
#define OFF_OTNN (OFF_OTAA + (size_t)64)
#define OFF_OTLN (OFF_OTNN + (size_t)64)
#define OFF_OTGN (OFF_OTLN + (size_t)64)
#define OFF_OTTT (OFF_OTGN + (size_t)64)

__device__ __forceinline__ float eps_at(int it) {
    return (it < 12) ? ldexpf(8.0f, -it) : 0.0025f;
}

__device__ __forceinline__ float block_sum256(float v, float* red, int tid) {
    #pragma unroll
    for (int off = 1; off < 64; off <<= 1) v += __shfl_xor(v, off);
    if ((tid & 63) == 0) red[tid >> 6] = v;
    __syncthreads();
    return red[0] + red[1] + red[2] + red[3];
}

// Two-pass LSE over LDS-resident data, no register arrays (spill-proof)
template<int LEN, int STRIDE>
__device__ __forceinline__ float lse_val(const float* __restrict__ pot,
                                         const float* __restrict__ Crow,
                                         float eps, float ieps) {
    float m0 = -3.4e38f, m1 = -3.4e38f, m2 = -3.4e38f, m3 = -3.4e38f;
    #pragma unroll
    for (int r = 0; r < LEN; ++r) {
        float u = pot[r] - Crow[(size_t)r * STRIDE];
        if ((r & 3) == 0) m0 = fmaxf(m0, u);
        else if ((r & 3) == 1) m1 = fmaxf(m1, u);
        else if ((r & 3) == 2) m2 = fmaxf(m2, u);
        else m3 = fmaxf(m3, u);
    }
    float m = fmaxf(fmaxf(m0, m1), fmaxf(m2, m3));
    float ie2 = ieps * LOG2E;
    float s0 = 0.f, s1 = 0.f, s2 = 0.f, s3 = 0.f;
    #pragma unroll
    for (int r = 0; r < LEN; ++r) {
        float e = exp2f((pot[r] - Crow[(size_t)r * STRIDE] - m) * ie2);
        if ((r & 3) == 0) s0 += e;
        else if ((r & 3) == 1) s1 += e;
        else if ((r & 3) == 2) s2 += e;
        else s3 += e;
    }
    float s = (s0 + s1) + (s2 + s3);
    return fmaf(eps * LN2, __log2f(s), m);
}

// ---------------- K0: 0.5 * squared norms ----------------
__global__ __launch_bounds__(256) void sq_kernel(const float* __restrict__ anchor,
                                                 const float* __restrict__ neg,
                                                 const float* __restrict__ t0,
                                                 float* __restrict__ ws) {
    int gw   = (blockIdx.x * 256 + threadIdx.x) >> 6;
    int lane = threadIdx.x & 63;
    const int nA = NB * LA, nN = NB * NNEG, nT = NCLS * NREF;
    if (gw >= nA + nN + nT) return;
    const float* row; float* outp;
    if (gw < nA)           { row = anchor + (size_t)gw * DD;          outp = ws + OFF_SQA + gw; }
    else if (gw < nA + nN) { int r = gw - nA;      row = neg + (size_t)r * DD; outp = ws + OFF_SQN + r; }
    else                   { int r = gw - nA - nN; row = t0  + (size_t)r * DD; outp = ws + OFF_SQT + r; }
    const float4* r4 = (const float4*)row;
    float4 u = r4[lane * 2], v = r4[lane * 2 + 1];
    float s = u.x*u.x + u.y*u.y + u.z*u.z + u.w*u.w
            + v.x*v.x + v.y*v.y + v.z*v.z + v.w*v.w;
    #pragma unroll
    for (int off = 1; off < 64; off <<= 1) s += __shfl_xor(s, off);
    if (lane == 0) *outp = 0.5f * s;
}

// ---------------- K1: cost matrices (cross written transposed) ----------------
#define TS 64
#define KC 16
__global__ __launch_bounds__(256) void cost_kernel(const float* __restrict__ anchor,
                                                   const float* __restrict__ neg,
                                                   const float* __restrict__ t0,
                                                   const int* __restrict__ gneg,
                                                   float* __restrict__ ws) {
    __shared__ __align__(16) float As[KC][TS];
    __shared__ __align__(16) float Bs[KC][TS];
    int bid = blockIdx.x, tid = threadIdx.x;
    const float *X, *Y, *sqx, *sqy;
    float* Cout; int N, M, ldc, r0, c0;
    bool tr = false;
    if (bid < 2048) {                     // cross
        int b = bid >> 5, t = bid & 31; r0 = (t >> 3) * 64; c0 = (t & 7) * 64;
        X = anchor + (size_t)b * LA * DD; Y = t0; N = LA; M = 500; ldc = 500;
        Cout = ws + OFF_CX + (size_t)b * 500 * 256;
        sqx = ws + OFF_SQA + b * LA; sqy = ws + OFF_SQT;
        tr = true;
    } else if (bid < 3072) {              // aa
        int b2 = bid - 2048; int b = b2 >> 4, t = b2 & 15; r0 = (t >> 2) * 64; c0 = (t & 3) * 64;
        X = Y = anchor + (size_t)b * LA * DD; N = M = LA; ldc = LA;
        Cout = ws + OFF_CAA + (size_t)b * LA * LA;
        sqx = sqy = ws + OFF_SQA + b * LA;
    } else if (bid < 3328) {              // nn
        int b2 = bid - 3072; int b = b2 >> 2, t = b2 & 3; r0 = (t >> 1) * 64; c0 = (t & 1) * 64;
        X = Y = neg + (size_t)b * NNEG * DD; N = M = NNEG; ldc = NNEG;
        Cout = ws + OFF_CNN + (size_t)b * NNEG * NNEG;
        sqx = sqy = ws + OFF_SQN + b * NNEG;
    } else if (bid < 3456) {              // ln
        int b2 = bid - 3328; int b = b2 >> 1; r0 = 0; c0 = (b2 & 1) * 64;
        X = t0 + (size_t)9 * NREF * DD; Y = neg + (size_t)b * NNEG * DD;
        N = NREF; M = NNEG; ldc = NNEG;
        Cout = ws + OFF_CLN + (size_t)b * NREF * NNEG;
        sqx = ws + OFF_SQT + 9 * NREF; sqy = ws + OFF_SQN + b * NNEG;
    } else if (bid < 3584) {              // gn
        int b2 = bid - 3456; int b = b2 >> 1; r0 = 0; c0 = (b2 & 1) * 64;
        int gc = gneg[b];
        X = t0 + (size_t)gc * NREF * DD; Y = neg + (size_t)b * NNEG * DD;
        N = NREF; M = NNEG; ldc = NNEG;
        Cout = ws + OFF_CGN + (size_t)b * NREF * NNEG;
        sqx = ws + OFF_SQT + gc * NREF; sqy = ws + OFF_SQN + b * NNEG;
    } else {                              // tt
        int c = bid - 3584; r0 = 0; c0 = 0;
        X = Y = t0 + (size_t)c * NREF * DD; N = M = NREF; ldc = NREF;
        Cout = ws + OFF_CTT + (size_t)c * NREF * NREF;
        sqx = sqy = ws + OFF_SQT + c * NREF;
    }
    int lr = tid >> 2, lk = (tid & 3) << 2;
    int tx = tid & 15, ty = tid >> 4;
    bool xok = (r0 + lr) < N, yok = (c0 + lr) < M;
    const float* xrow = X + (size_t)(r0 + lr) * DD;
    const float* yrow = Y + (size_t)(c0 + lr) * DD;
    float acc[4][4];
    #pragma unroll
    for (int a = 0; a < 4; a++)
        #pragma unroll
        for (int b = 0; b < 4; b++) acc[a][b] = 0.f;
    for (int k0 = 0; k0 < DD; k0 += KC) {
        float4 xa = xok ? *(const float4*)(xrow + k0 + lk) : make_float4(0,0,0,0);
        float4 ya = yok ? *(const float4*)(yrow + k0 + lk) : make_float4(0,0,0,0);
        __syncthreads();
        As[lk+0][lr]=xa.x; As[lk+1][lr]=xa.y; As[lk+2][lr]=xa.z; As[lk+3][lr]=xa.w;
        Bs[lk+0][lr]=ya.x; Bs[lk+1][lr]=ya.y; Bs[lk+2][lr]=ya.z; Bs[lk+3][lr]=ya.w;
        __syncthreads();
        #pragma unroll
        for (int k = 0; k < KC; k++) {
            const float4 av = *(const float4*)&As[k][ty << 2];
            const float4 bv = *(const float4*)&Bs[k][tx << 2];
            acc[0][0]=fmaf(av.x,bv.x,acc[0][0]); acc[0][1]=fmaf(av.x,bv.y,acc[0][1]);
            acc[0][2]=fmaf(av.x,bv.z,acc[0][2]); acc[0][3]=fmaf(av.x,bv.w,acc[0][3]);
            acc[1][0]=fmaf(av.y,bv.x,acc[1][0]); acc[1][1]=fmaf(av.y,bv.y,acc[1][1]);
            acc[1][2]=fmaf(av.y,bv.z,acc[1][2]); acc[1][3]=fmaf(av.y,bv.w,acc[1][3]);
            acc[2][0]=fmaf(av.z,bv.x,acc[2][0]); acc[2][1]=fmaf(av.z,bv.y,acc[2][1]);
            acc[2][2]=fmaf(av.z,bv.z,acc[2][2]); acc[2][3]=fmaf(av.z,bv.w,acc[2][3]);
            acc[3][0]=fmaf(av.w,bv.x,acc[3][0]); acc[3][1]=fmaf(av.w,bv.y,acc[3][1]);
            acc[3][2]=fmaf(av.w,bv.z,acc[3][2]); acc[3][3]=fmaf(av.w,bv.w,acc[3][3]);
        }
    }
    #pragma unroll
    for (int a = 0; a < 4; a++) {
        int n = r0 + (ty << 2) + a;
        if (n < N) {
            float sx = sqx[n];
            #pragma unroll
            for (int b = 0; b < 4; b++) {
                int m = c0 + (tx << 2) + b;
                if (m < M) {
                    float v = sx + sqy[m] - acc[a][b];
                    if (tr) Cout[(size_t)m * 256 + n] = v;
                    else    Cout[(size_t)n * ldc + m] = v;
                }
            }
        }
    }
}

// ---------------- K2a: aa Sinkhorn, C register-resident ----------------
// 1024 threads: thread (q,c) holds C[q*64 .. q*64+63][c] in 64 VGPRs.
__global__ __launch_bounds__(1024, 1) void aa_sink_reg(const float* __restrict__ weight,
                                                       float* __restrict__ ws) {
    __shared__ float ahS[256];
    __shared__ float pm[4][256];
    __shared__ float ps[4][256];
    __shared__ float red[16];
    int i = blockIdx.x, tid = threadIdx.x;
    int w = tid >> 6, lane = tid & 63;
    int q = w >> 2;                          // row quarter 0..3
    int c = ((w & 3) << 6) | lane;           // column 0..255
    const float* Cg = ws + OFF_CAA + ((size_t)i << 16);
    float Creg[64];
    #pragma unroll
    for (int k = 0; k < 64; ++k)
        Creg[k] = Cg[(size_t)((q << 6) + k) * 256 + c];
    float wgt = weight[(size_t)i * LA + c];
    float la = (wgt > 0.f) ? __logf(fmaxf(wgt, 1e-30f)) : -1e9f;
    float h = 0.f, fs = 0.f;
    if (q == 0) ahS[c] = 8.0f * la;          // app 0: eps=8, h=0
    __syncthreads();
    int rbase = q << 6;
    for (int app = 0; app < 54; ++app) {
        float eps = eps_at(app >> 1);
        // pass A: partial max over this thread's 64 rows
        float m0 = -3.4e38f, m1 = -3.4e38f, m2 = -3.4e38f, m3 = -3.4e38f;
        #pragma unroll
        for (int k = 0; k < 64; ++k) {
            float u = ahS[rbase + k] - Creg[k];
            if ((k & 3) == 0) m0 = fmaxf(m0, u);
            else if ((k & 3) == 1) m1 = fmaxf(m1, u);
            else if ((k & 3) == 2) m2 = fmaxf(m2, u);
            else m3 = fmaxf(m3, u);
        }
        pm[q][c] = fmaxf(fmaxf(m0, m1), fmaxf(m2, m3));
        __syncthreads();
        float m = fmaxf(fmaxf(pm[0][c], pm[1][c]), fmaxf(pm[2][c], pm[3][c]));
        // pass B: partial sum of exps
        float ie2 = (1.0f / eps) * LOG2E;
        float s0 = 0.f, s1 = 0.f, s2 = 0.f, s3 = 0.f;
        #pragma unroll
        for (int k = 0; k < 64; ++k) {
            float e = exp2f((ahS[rbase + k] - Creg[k] - m) * ie2);
            if ((k & 3) == 0) s0 += e;
            else if ((k & 3) == 1) s1 += e;
            else if ((k & 3) == 2) s2 += e;
            else s3 += e;
        }
        ps[q][c] = (s0 + s1) + (s2 + s3);
        __syncthreads();
        // pass C: combine, update h, publish next ah
        float s = (ps[0][c] + ps[1][c]) + (ps[2][c] + ps[3][c]);
        h = -fmaf(eps * LN2, __log2f(s), m);
        if (app == 52) fs = h;
        if (q == 0) {
            float epsn = eps_at((app + 1) >> 1);
            ahS[c] = fmaf(epsn, la, h);
        }
        __syncthreads();
    }
    float contrib = (q == 0) ? wgt * (fs + h) : 0.f;
    #pragma unroll
    for (int off = 1; off < 64; off <<= 1) contrib += __shfl_xor(contrib, off);
    if (lane == 0) red[w] = contrib;
    __syncthreads();
    if (tid == 0) {
        float s = 0.f;
        #pragma unroll
        for (int k = 0; k < 16; ++k) s += red[k];
        ws[OFF_OTAA + i] = s;
    }
}

// ---------------- K2b: cross + nn + ln + gn + tt ----------------
#define SMEMF 13328
#define LB50  (-3.9120230054f)

template<int N, int M, bool SYM>
__device__ void small_sink(const float* __restrict__ Cglob, float* __restrict__ smem,
                           float* __restrict__ red, int tid, float* __restrict__ outp) {
    constexpr int Mp = M + 1, Np = N + 1;
    float* Cs  = smem;
    float* CsT = smem + N * Mp;
    float* fS  = smem + 10496;
    float* gS  = smem + 10624;
    for (int e = tid; e < N * M; e += 256) {
        int n = e / M, mm = e - n * M;
        Cs[n * Mp + mm] = Cglob[e];
    }
    __syncthreads();
    if (!SYM) {
        for (int e = tid; e < N * M; e += 256) {
            int n = e / M, mm = e - n * M;
            CsT[mm * Np + n] = Cs[n * Mp + mm];
        }
    }
    if (tid < M) gS[tid] = 0.f;
    __syncthreads();
    constexpr float lac = (N == 100) ? -4.6051701860f : -3.9120230054f;
    constexpr float lbc = (M == 100) ? -4.6051701860f : -3.9120230054f;
    for (int it = 0; it < NITER; ++it) {
        float eps = eps_at(it), ieps = 1.0f / eps;
        if (tid < N) {
            float L = lse_val<M, 1>(gS, &Cs[tid * Mp], eps, ieps);
            fS[tid] = -fmaf(eps, lbc, L);
        }
        __syncthreads();
        if (tid < M) {
            float L = SYM ? lse_val<N, 1>(fS, &Cs[tid * Mp], eps, ieps)
                          : lse_val<N, 1>(fS, &CsT[tid * Np], eps, ieps);
            gS[tid] = -fmaf(eps, lac, L);
        }
        __syncthreads();
    }
    float contrib = 0.f;
    if (tid < N) contrib += fS[tid] * (1.0f / N);
    if (tid < M) contrib += gS[tid] * (1.0f / M);
    contrib = block_sum256(contrib, red, tid);
    if (tid == 0) *outp = contrib;
}

__global__ __launch_bounds__(256, 3) void sink_rest(const float* __restrict__ weight,
                                                    float* __restrict__ ws) {
    __shared__ float smem[SMEMF];
    float* red = smem + 13320;
    int bid = blockIdx.x, tid = threadIdx.x;

    if (bid < 640) {
        // ---- cross: C^T in LDS [50][260]; thread-per-output f; 16-lane-group g ----
        int ii = bid;
        int i = ii / 10, c = ii - i * 10;
        float* CsT = smem;                 // [50][260]
        float* agS = smem + 13000;         // [256] = eps*la + f
        float* gS  = smem + 13256;         // [64]
        const float* Cgbase = ws + OFF_CX + (size_t)i * (500 * 256) + (size_t)c * (50 * 256);
        for (int e = tid; e < 3200; e += 256) {
            int r = e >> 6, n4 = (e & 63) << 2;
            *(float4*)&CsT[r * 260 + n4] = *(const float4*)&Cgbase[(size_t)e << 2];
        }
        float w = weight[(size_t)i * LA + tid];
        float la_r = (w > 0.f) ? __logf(fmaxf(w, 1e-30f)) : -1e9f;
        if (tid < 64) gS[tid] = 0.f;
        __syncthreads();
        int grp = tid >> 4, j = tid & 15;
        for (int it = 0; it < NITER; ++it) {
            float eps = eps_at(it), ieps = 1.0f / eps;
            {
                float L = lse_val<50, 260>(gS, &CsT[tid], eps, ieps);
                float f = -fmaf(eps, LB50, L);
                agS[tid] = fmaf(eps, la_r, f);
            }
            __syncthreads();
            float ie2 = ieps * LOG2E;
            for (int o = grp; o < 50; o += 16) {
                const float* Cr = &CsT[o * 260];
                float up[16];
                #pragma unroll
                for (int k = 0; k < 16; ++k) up[k] = agS[j + (k << 4)] - Cr[j + (k << 4)];
                float a0 = up[0], a1 = up[1], a2 = up[2], a3 = up[3];
                #pragma unroll
                for (int k = 4; k < 16; ++k) {
                    if ((k & 3) == 0) a0 = fmaxf(a0, up[k]);
                    else if ((k & 3) == 1) a1 = fmaxf(a1, up[k]);
                    else if ((k & 3) == 2) a2 = fmaxf(a2, up[k]);
                    else a3 = fmaxf(a3, up[k]);
                }
                float m = fmaxf(fmaxf(a0, a1), fmaxf(a2, a3));
                #pragma unroll
                for (int off = 1; off < 16; off <<= 1) m = fmaxf(m, __shfl_xor(m, off));
                float s0 = 0.f, s1 = 0.f, s2 = 0.f, s3 = 0.f;
                #pragma unroll
                for (int k = 0; k < 16; ++k) {
                    float e = exp2f((up[k] - m) * ie2);
                    if ((k & 3) == 0) s0 += e;
                    else if ((k & 3) == 1) s1 += e;
                    else if ((k & 3) == 2) s2 += e;
                    else s3 += e;
                }
                float s = (s0 + s1) + (s2 + s3);
                #pragma unroll
                for (int off = 1; off < 16; off <<= 1) s += __shfl_xor(s, off);
                if (j == 0) gS[o] = -fmaf(eps * LN2, __log2f(s), m);
            }
            __syncthreads();
        }
        float f_t = agS[tid] - 0.0025f * la_r;
        float contrib = w * f_t + (tid < 50 ? 0.02f * gS[tid] : 0.f);
        contrib = block_sum256(contrib, red, tid);
        if (tid == 0) ws[OFF_OTX + ii] = contrib;

    } else if (bid < 704) {
        int q = bid - 640;
        small_sink<100, 100, true>(ws + OFF_CNN + (size_t)q * 10000, smem, red, tid,
                                   ws + OFF_OTNN + q);
    } else if (bid < 832) {
        int q = bid - 704;
        const float* base = (q < 64) ? (ws + OFF_CLN + (size_t)q * 5000)
                                     : (ws + OFF_CGN + (size_t)(q - 64) * 5000);
        float* outp = (q < 64) ? (ws + OFF_OTLN + q) : (ws + OFF_OTGN + (q - 64));
        small_sink<50, 100, false>(base, smem, red, tid, outp);
    } else {
        int q = bid - 832;
        small_sink<50, 50, true>(ws + OFF_CTT + (size_t)q * 2500, smem, red, tid,
                                 ws + OFF_OTTT + q);
    }
}

// ---------------- K3: final loss assembly ----------------
__global__ void assemble_kernel(const int* __restrict__ grade, const int* __restrict__ gneg,
                                const float* __restrict__ ws, float* __restrict__ out) {
    int i = threadIdx.x;
    float total = 0.f;
    if (i < 64) {
        float aa  = ws[OFF_OTAA + i];
        float nn  = ws[OFF_OTNN + i];
        float lnv = ws[OFF_OTLN + i];
        float gnv = ws[OFF_OTGN + i];
        int g  = grade[i];
        int gi = gneg[i];
        float tt9 = ws[OFF_OTTT + 9];
        float ttg = ws[OFF_OTTT + gi];
        float Slast = lnv - 0.5f * tt9 - 0.5f * nn;
        float Sgn   = gnv - 0.5f * ttg - 0.5f * nn;
        float Sv[10];
        #pragma unroll
        for (int k = 0; k < 10; k++)
            Sv[k] = ws[OFF_OTX + i * 10 + k] - 0.5f * aa - 0.5f * ws[OFF_OTTT + k];
        float pos = 0.f;
        #pragma unroll
        for (int k = 0; k < 10; k++) pos = (k == g) ? Sv[k] : pos;
        float hc = 0.f;
        #pragma unroll
        for (int k = 0; k < 10; k++)
            if (k != g) hc += fmaxf(pos - Sv[k] + MARGIN, 0.f);
        float hn = fmaxf(pos - Slast + MARGIN, 0.f);
        total = hc + hn + fabsf(Sgn - Slast);
    }
    #pragma unroll
    for (int off = 1; off < 64; off <<= 1) total += __shfl_xor(total, off);
    if (i == 0) out[0] = total * (1.0f / 64.0f);
}

extern "C" void kernel_launch(void* const* d_in, const int* in_sizes, int n_in,
                              void* d_out, int out_size, void* d_ws, size_t ws_size,
                              hipStream_t stream) {
    const float* anchor = (const float*)d_in[0];
    const int*   grade  = (const int*)d_in[2];
    const float* weight = (const float*)d_in[3];
    const float* neg    = (const float*)d_in[4];
    const int*   gneg   = (const int*)d_in[5];
    const float* t0     = (const float*)d_in[6];
    float* ws  = (float*)d_ws;
    float* out = (float*)d_out;

    sq_kernel      <<<5821, 256, 0, stream>>>(anchor, neg, t0, ws);
    cost_kernel    <<<3594, 256, 0, stream>>>(anchor, neg, t0, gneg, ws);
    aa_sink_reg    <<<64, 1024, 0, stream>>>(weight, ws);
    sink_rest      <<<842, 256, 0, stream>>>(weight, ws);
    assemble_kernel<<<1, 64, 0, stream>>>(grade, gneg, ws, out);
}

// Round 5
// 787.476 us; speedup vs baseline: 9.1770x; 1.0104x over previous
//
#include <hip/hip_runtime.h>

// Problem constants
#define NB   64
#define LA   256
#define DD   512
#define NCLS 10
#define NREF 50
#define NNEG 100
#define MARGIN 10.0f
#define NITER 27

#define LOG2E 1.44269504f
#define LN2   0.69314718f

// ---- workspace layout (float offsets) ----
// cross cost stored TRANSPOSED: [b][500][256] (t0-point major)
#define OFF_CX   ((size_t)0)
#define SZ_CX    ((size_t)64*500*256)
#define OFF_CAA  (OFF_CX + SZ_CX)                 // aa cost     [64][256][256] (symmetric)
#define SZ_CAA   ((size_t)64*256*256)
#define OFF_CNN  (OFF_CAA + SZ_CAA)               // nn cost     [64][100][100] (symmetric)
#define SZ_CNN   ((size_t)64*100*100)
#define OFF_CLN  (OFF_CNN + SZ_CNN)               // ln cost     [64][50][100]
#define SZ_CLN   ((size_t)64*50*100)
#define OFF_CGN  (OFF_CLN + SZ_CLN)               // gn cost     [64][50][100]
#define SZ_CGN   ((size_t)64*50*100)
#define OFF_CTT  (OFF_CGN + SZ_CGN)               // tt cost     [10][50][50] (symmetric)
#define SZ_CTT   ((size_t)10*50*50)
#define OFF_SQA  (OFF_CTT + SZ_CTT)
#define OFF_SQN  (OFF_SQA + (size_t)64*256)
#define OFF_SQT  (OFF_SQN + (size_t)64*100)
#define OFF_OTX  (OFF_SQT + (size_t)500)
#define OFF_OTAA (OFF_OTX + (size_t)640)
#define OFF_OTNN (OFF_OTAA + (size_t)64)
#define OFF_OTLN (OFF_OTNN + (size_t)64)
#define OFF_OTGN (OFF_OTLN + (size_t)64)
#define OFF_OTTT (OFF_OTGN + (size_t)64)

__device__ __forceinline__ float eps_at(int it) {
    return (it < 12) ? ldexpf(8.0f, -it) : 0.0025f;
}

__device__ __forceinline__ float block_sum256(float v, float* red, int tid) {
    #pragma unroll
    for (int off = 1; off < 64; off <<= 1) v += __shfl_xor(v, off);
    if ((tid & 63) == 0) red[tid >> 6] = v;
    __syncthreads();
    return red[0] + red[1] + red[2] + red[3];
}

// Two-pass LSE over LDS-resident data, no register arrays (used by small_sink)
template<int LEN, int STRIDE>
__device__ __forceinline__ float lse_val(const float* __restrict__ pot,
                                         const float* __restrict__ Crow,
                                         float eps, float ieps) {
    float m0 = -3.4e38f, m1 = -3.4e38f, m2 = -3.4e38f, m3 = -3.4e38f;
    #pragma unroll
    for (int r = 0; r < LEN; ++r) {
        float u = pot[r] - Crow[(size_t)r * STRIDE];
        if ((r & 3) == 0) m0 = fmaxf(m0, u);
        else if ((r & 3) == 1) m1 = fmaxf(m1, u);
        else if ((r & 3) == 2) m2 = fmaxf(m2, u);
        else m3 = fmaxf(m3, u);
    }
    float m = fmaxf(fmaxf(m0, m1), fmaxf(m2, m3));
    float ie2 = ieps * LOG2E;
    float s0 = 0.f, s1 = 0.f, s2 = 0.f, s3 = 0.f;
    #pragma unroll
    for (int r = 0; r < LEN; ++r) {
        float e = exp2f((pot[r] - Crow[(size_t)r * STRIDE] - m) * ie2);
        if ((r & 3) == 0) s0 += e;
        else if ((r & 3) == 1) s1 += e;
        else if ((r & 3) == 2) s2 += e;
        else s3 += e;
    }
    float s = (s0 + s1) + (s2 + s3);
    return fmaf(eps * LN2, __log2f(s), m);
}

// ---------------- K0: 0.5 * squared norms ----------------
__global__ __launch_bounds__(256) void sq_kernel(const float* __restrict__ anchor,
                                                 const float* __restrict__ neg,
                                                 const float* __restrict__ t0,
                                                 float* __restrict__ ws) {
    int gw   = (blockIdx.x * 256 + threadIdx.x) >> 6;
    int lane = threadIdx.x & 63;
    const int nA = NB * LA, nN = NB * NNEG, nT = NCLS * NREF;
    if (gw >= nA + nN + nT) return;
    const float* row; float* outp;
    if (gw < nA)           { row = anchor + (size_t)gw * DD;          outp = ws + OFF_SQA + gw; }
    else if (gw < nA + nN) { int r = gw - nA;      row = neg + (size_t)r * DD; outp = ws + OFF_SQN + r; }
    else                   { int r = gw - nA - nN; row = t0  + (size_t)r * DD; outp = ws + OFF_SQT + r; }
    const float4* r4 = (const float4*)row;
    float4 u = r4[lane * 2], v = r4[lane * 2 + 1];
    float s = u.x*u.x + u.y*u.y + u.z*u.z + u.w*u.w
            + v.x*v.x + v.y*v.y + v.z*v.z + v.w*v.w;
    #pragma unroll
    for (int off = 1; off < 64; off <<= 1) s += __shfl_xor(s, off);
    if (lane == 0) *outp = 0.5f * s;
}

// ---------------- K1: cost matrices — 128x128 tile, 8x8 micro, K=16 ----------------
#define CTM 128
#define CTK 16
__global__ __launch_bounds__(256) void cost128(const float* __restrict__ anchor,
                                               const float* __restrict__ neg,
                                               const float* __restrict__ t0,
                                               const int* __restrict__ gneg,
                                               float* __restrict__ ws) {
    __shared__ __align__(16) float As[CTK][CTM];
    __shared__ __align__(16) float Bs[CTK][CTM];
    int bid = blockIdx.x, tid = threadIdx.x;
    const float *X, *Y, *sqx, *sqy;
    float* Cout; int N, M, ldc, r0, c0;
    bool tr = false;
    if (bid < 512) {                      // cross: anchor[b] x t0 (256x500), store [m][n]
        int b = bid >> 3, t = bid & 7;
        r0 = (t >> 2) * 128; c0 = (t & 3) * 128;
        X = anchor + (size_t)b * LA * DD; Y = t0; N = LA; M = 500; ldc = 500;
        Cout = ws + OFF_CX + (size_t)b * 500 * 256;
        sqx = ws + OFF_SQA + b * LA; sqy = ws + OFF_SQT;
        tr = true;
    } else if (bid < 768) {               // aa (256x256)
        int b2 = bid - 512; int b = b2 >> 2, t = b2 & 3;
        r0 = (t >> 1) * 128; c0 = (t & 1) * 128;
        X = Y = anchor + (size_t)b * LA * DD; N = M = LA; ldc = LA;
        Cout = ws + OFF_CAA + (size_t)b * LA * LA;
        sqx = sqy = ws + OFF_SQA + b * LA;
    } else if (bid < 832) {               // nn (100x100)
        int b = bid - 768; r0 = 0; c0 = 0;
        X = Y = neg + (size_t)b * NNEG * DD; N = M = NNEG; ldc = NNEG;
        Cout = ws + OFF_CNN + (size_t)b * NNEG * NNEG;
        sqx = sqy = ws + OFF_SQN + b * NNEG;
    } else if (bid < 896) {               // ln (50x100)
        int b = bid - 832; r0 = 0; c0 = 0;
        X = t0 + (size_t)9 * NREF * DD; Y = neg + (size_t)b * NNEG * DD;
        N = NREF; M = NNEG; ldc = NNEG;
        Cout = ws + OFF_CLN + (size_t)b * NREF * NNEG;
        sqx = ws + OFF_SQT + 9 * NREF; sqy = ws + OFF_SQN + b * NNEG;
    } else if (bid < 960) {               // gn (50x100)
        int b = bid - 896; r0 = 0; c0 = 0;
        int gc = gneg[b];
        X = t0 + (size_t)gc * NREF * DD; Y = neg + (size_t)b * NNEG * DD;
        N = NREF; M = NNEG; ldc = NNEG;
        Cout = ws + OFF_CGN + (size_t)b * NREF * NNEG;
        sqx = ws + OFF_SQT + gc * NREF; sqy = ws + OFF_SQN + b * NNEG;
    } else {                              // tt (50x50)
        int c = bid - 960; r0 = 0; c0 = 0;
        X = Y = t0 + (size_t)c * NREF * DD; N = M = NREF; ldc = NREF;
        Cout = ws + OFF_CTT + (size_t)c * NREF * NREF;
        sqx = sqy = ws + OFF_SQT + c * NREF;
    }
    int row = tid & 127, kq = tid >> 7;   // kq 0/1: k-offset 8*kq
    int tx = tid & 15, ty = tid >> 4;
    bool xok = (r0 + row) < N, yok = (c0 + row) < M;
    const float* xrow = X + (size_t)(r0 + row) * DD + kq * 8;
    const float* yrow = Y + (size_t)(c0 + row) * DD + kq * 8;
    float acc[8][8];
    #pragma unroll
    for (int a = 0; a < 8; a++)
        #pragma unroll
        for (int b = 0; b < 8; b++) acc[a][b] = 0.f;
    for (int k0 = 0; k0 < DD; k0 += CTK) {
        float4 xa0 = xok ? *(const float4*)(xrow + k0)     : make_float4(0,0,0,0);
        float4 xa1 = xok ? *(const float4*)(xrow + k0 + 4) : make_float4(0,0,0,0);
        float4 ya0 = yok ? *(const float4*)(yrow + k0)     : make_float4(0,0,0,0);
        float4 ya1 = yok ? *(const float4*)(yrow + k0 + 4) : make_float4(0,0,0,0);
        __syncthreads();
        int kb = kq * 8;
        As[kb+0][row]=xa0.x; As[kb+1][row]=xa0.y; As[kb+2][row]=xa0.z; As[kb+3][row]=xa0.w;
        As[kb+4][row]=xa1.x; As[kb+5][row]=xa1.y; As[kb+6][row]=xa1.z; As[kb+7][row]=xa1.w;
        Bs[kb+0][row]=ya0.x; Bs[kb+1][row]=ya0.y; Bs[kb+2][row]=ya0.z; Bs[kb+3][row]=ya0.w;
        Bs[kb+4][row]=ya1.x; Bs[kb+5][row]=ya1.y; Bs[kb+6][row]=ya1.z; Bs[kb+7][row]=ya1.w;
        __syncthreads();
        #pragma unroll
        for (int k = 0; k < CTK; k++) {
            float4 a0 = *(const float4*)&As[k][ty << 3];
            float4 a1 = *(const float4*)&As[k][(ty << 3) + 4];
            float4 b0 = *(const float4*)&Bs[k][tx << 3];
            float4 b1 = *(const float4*)&Bs[k][(tx << 3) + 4];
            float av[8] = {a0.x,a0.y,a0.z,a0.w,a1.x,a1.y,a1.z,a1.w};
            float bv[8] = {b0.x,b0.y,b0.z,b0.w,b1.x,b1.y,b1.z,b1.w};
            #pragma unroll
            for (int a = 0; a < 8; a++)
                #pragma unroll
                for (int b = 0; b < 8; b++)
                    acc[a][b] = fmaf(av[a], bv[b], acc[a][b]);
        }
    }
    #pragma unroll
    for (int a = 0; a < 8; a++) {
        int n = r0 + (ty << 3) + a;
        if (n < N) {
            float sx = sqx[n];
            #pragma unroll
            for (int b = 0; b < 8; b++) {
                int m = c0 + (tx << 3) + b;
                if (m < M) {
                    float v = sx + sqy[m] - acc[a][b];
                    if (tr) Cout[(size_t)m * 256 + n] = v;
                    else    Cout[(size_t)n * ldc + m] = v;
                }
            }
        }
    }
}

// ---------------- K2a: aa Sinkhorn, C register-resident (unchanged) ----------------
__global__ __launch_bounds__(1024, 1) void aa_sink_reg(const float* __restrict__ weight,
                                                       float* __restrict__ ws) {
    __shared__ float ahS[256];
    __shared__ float pm[4][256];
    __shared__ float ps[4][256];
    __shared__ float red[16];
    int i = blockIdx.x, tid = threadIdx.x;
    int w = tid >> 6, lane = tid & 63;
    int q = w >> 2;
    int c = ((w & 3) << 6) | lane;
    const float* Cg = ws + OFF_CAA + ((size_t)i << 16);
    float Creg[64];
    #pragma unroll
    for (int k = 0; k < 64; ++k)
        Creg[k] = Cg[(size_t)((q << 6) + k) * 256 + c];
    float wgt = weight[(size_t)i * LA + c];
    float la = (wgt > 0.f) ? __logf(fmaxf(wgt, 1e-30f)) : -1e9f;
    float h = 0.f, fs = 0.f;
    if (q == 0) ahS[c] = 8.0f * la;
    __syncthreads();
    int rbase = q << 6;
    for (int app = 0; app < 54; ++app) {
        float eps = eps_at(app >> 1);
        float m0 = -3.4e38f, m1 = -3.4e38f, m2 = -3.4e38f, m3 = -3.4e38f;
        #pragma unroll
        for (int k = 0; k < 64; ++k) {
            float u = ahS[rbase + k] - Creg[k];
            if ((k & 3) == 0) m0 = fmaxf(m0, u);
            else if ((k & 3) == 1) m1 = fmaxf(m1, u);
            else if ((k & 3) == 2) m2 = fmaxf(m2, u);
            else m3 = fmaxf(m3, u);
        }
        pm[q][c] = fmaxf(fmaxf(m0, m1), fmaxf(m2, m3));
        __syncthreads();
        float m = fmaxf(fmaxf(pm[0][c], pm[1][c]), fmaxf(pm[2][c], pm[3][c]));
        float ie2 = (1.0f / eps) * LOG2E;
        float s0 = 0.f, s1 = 0.f, s2 = 0.f, s3 = 0.f;
        #pragma unroll
        for (int k = 0; k < 64; ++k) {
            float e = exp2f((ahS[rbase + k] - Creg[k] - m) * ie2);
            if ((k & 3) == 0) s0 += e;
            else if ((k & 3) == 1) s1 += e;
            else if ((k & 3) == 2) s2 += e;
            else s3 += e;
        }
        ps[q][c] = (s0 + s1) + (s2 + s3);
        __syncthreads();
        float s = (ps[0][c] + ps[1][c]) + (ps[2][c] + ps[3][c]);
        h = -fmaf(eps * LN2, __log2f(s), m);
        if (app == 52) fs = h;
        if (q == 0) {
            float epsn = eps_at((app + 1) >> 1);
            ahS[c] = fmaf(epsn, la, h);
        }
        __syncthreads();
    }
    float contrib = (q == 0) ? wgt * (fs + h) : 0.f;
    #pragma unroll
    for (int off = 1; off < 64; off <<= 1) contrib += __shfl_xor(contrib, off);
    if (lane == 0) red[w] = contrib;
    __syncthreads();
    if (tid == 0) {
        float s = 0.f;
        #pragma unroll
        for (int k = 0; k < 16; ++k) s += red[k];
        ws[OFF_OTAA + i] = s;
    }
}

// ---------------- K2b: cross + nn + ln + gn + tt ----------------
#define SMEMF 13324
#define LB50  (-3.9120230054f)

template<int N, int M, bool SYM>
__device__ void small_sink(const float* __restrict__ Cglob, float* __restrict__ smem,
                           float* __restrict__ red, int tid, float* __restrict__ outp) {
    constexpr int Mp = M + 1, Np = N + 1;
    float* Cs  = smem;
    float* CsT = smem + N * Mp;
    float* fS  = smem + 10496;
    float* gS  = smem + 10624;
    for (int e = tid; e < N * M; e += 256) {
        int n = e / M, mm = e - n * M;
        Cs[n * Mp + mm] = Cglob[e];
    }
    __syncthreads();
    if (!SYM) {
        for (int e = tid; e < N * M; e += 256) {
            int n = e / M, mm = e - n * M;
            CsT[mm * Np + n] = Cs[n * Mp + mm];
        }
    }
    if (tid < M) gS[tid] = 0.f;
    __syncthreads();
    constexpr float lac = (N == 100) ? -4.6051701860f : -3.9120230054f;
    constexpr float lbc = (M == 100) ? -4.6051701860f : -3.9120230054f;
    for (int it = 0; it < NITER; ++it) {
        float eps = eps_at(it), ieps = 1.0f / eps;
        if (tid < N) {
            float L = lse_val<M, 1>(gS, &Cs[tid * Mp], eps, ieps);
            fS[tid] = -fmaf(eps, lbc, L);
        }
        __syncthreads();
        if (tid < M) {
            float L = SYM ? lse_val<N, 1>(fS, &Cs[tid * Mp], eps, ieps)
                          : lse_val<N, 1>(fS, &CsT[tid * Np], eps, ieps);
            gS[tid] = -fmaf(eps, lac, L);
        }
        __syncthreads();
    }
    float contrib = 0.f;
    if (tid < N) contrib += fS[tid] * (1.0f / N);
    if (tid < M) contrib += gS[tid] * (1.0f / M);
    contrib = block_sum256(contrib, red, tid);
    if (tid == 0) *outp = contrib;
}

__global__ __launch_bounds__(256, 3) void sink_rest(const float* __restrict__ weight,
                                                    float* __restrict__ ws) {
    __shared__ float smem[SMEMF];
    float* red = smem + 13320;
    int bid = blockIdx.x, tid = threadIdx.x;

    if (bid < 640) {
        // ---- cross: C^T [50][260] in LDS; f fully register-resident ----
        int ii = bid;
        int i = ii / 10, c = ii - i * 10;
        float* CsT = smem;                 // [50][260]
        float* agS = smem + 13000;         // [256] = eps*la + f
        float* gS  = smem + 13256;         // [64]
        const float* Cgbase = ws + OFF_CX + (size_t)i * (500 * 256) + (size_t)c * (50 * 256);
        for (int e = tid; e < 3200; e += 256) {
            int r = e >> 6, n4 = (e & 63) << 2;
            *(float4*)&CsT[r * 260 + n4] = *(const float4*)&Cgbase[(size_t)e << 2];
        }
        float w = weight[(size_t)i * LA + tid];
        float la_r = (w > 0.f) ? __logf(fmaxf(w, 1e-30f)) : -1e9f;
        if (tid < 64) gS[tid] = 0.f;
        __syncthreads();
        // own C-row (anchor tid, refs 0..49) in registers
        float Creg[50];
        #pragma unroll
        for (int r = 0; r < 50; ++r) Creg[r] = CsT[r * 260 + tid];
        int grp = tid >> 4, j = tid & 15;
        for (int it = 0; it < NITER; ++it) {
            float eps = eps_at(it), ieps = 1.0f / eps;
            float ie2 = ieps * LOG2E;
            // f-update: register two-pass LSE over 50 refs
            {
                float u[50];
                float m0 = -3.4e38f, m1 = -3.4e38f, m2 = -3.4e38f, m3 = -3.4e38f;
                #pragma unroll
                for (int r = 0; r < 50; ++r) {
                    float v = gS[r] - Creg[r];
                    u[r] = v;
                    if ((r & 3) == 0) m0 = fmaxf(m0, v);
                    else if ((r & 3) == 1) m1 = fmaxf(m1, v);
                    else if ((r & 3) == 2) m2 = fmaxf(m2, v);
                    else m3 = fmaxf(m3, v);
                }
                float m = fmaxf(fmaxf(m0, m1), fmaxf(m2, m3));
                float s0 = 0.f, s1 = 0.f, s2 = 0.f, s3 = 0.f;
                #pragma unroll
                for (int r = 0; r < 50; ++r) {
                    float e = exp2f((u[r] - m) * ie2);
                    if ((r & 3) == 0) s0 += e;
                    else if ((r & 3) == 1) s1 += e;
                    else if ((r & 3) == 2) s2 += e;
                    else s3 += e;
                }
                float L = fmaf(eps * LN2, __log2f((s0 + s1) + (s2 + s3)), m);
                float f = -fmaf(eps, LB50, L);
                agS[tid] = fmaf(eps, la_r, f);
            }
            __syncthreads();
            // g-update: 16-lane groups; ag cached in registers across o-passes
            float agr[16];
            #pragma unroll
            for (int k = 0; k < 16; ++k) agr[k] = agS[j + (k << 4)];
            for (int o = grp; o < 50; o += 16) {
                const float* Cr = &CsT[o * 260];
                float up[16];
                #pragma unroll
                for (int k = 0; k < 16; ++k) up[k] = agr[k] - Cr[j + (k << 4)];
                float a0 = up[0], a1 = up[1], a2 = up[2], a3 = up[3];
                #pragma unroll
                for (int k = 4; k < 16; ++k) {
                    if ((k & 3) == 0) a0 = fmaxf(a0, up[k]);
                    else if ((k & 3) == 1) a1 = fmaxf(a1, up[k]);
                    else if ((k & 3) == 2) a2 = fmaxf(a2, up[k]);
                    else a3 = fmaxf(a3, up[k]);
                }
                float m = fmaxf(fmaxf(a0, a1), fmaxf(a2, a3));
                #pragma unroll
                for (int off = 1; off < 16; off <<= 1) m = fmaxf(m, __shfl_xor(m, off));
                float s0 = 0.f, s1 = 0.f, s2 = 0.f, s3 = 0.f;
                #pragma unroll
                for (int k = 0; k < 16; ++k) {
                    float e = exp2f((up[k] - m) * ie2);
                    if ((k & 3) == 0) s0 += e;
                    else if ((k & 3) == 1) s1 += e;
                    else if ((k & 3) == 2) s2 += e;
                    else s3 += e;
                }
                float s = (s0 + s1) + (s2 + s3);
                #pragma unroll
                for (int off = 1; off < 16; off <<= 1) s += __shfl_xor(s, off);
                if (j == 0) gS[o] = -fmaf(eps * LN2, __log2f(s), m);
            }
            __syncthreads();
        }
        float f_t = agS[tid] - 0.0025f * la_r;
        float contrib = w * f_t + (tid < 50 ? 0.02f * gS[tid] : 0.f);
        contrib = block_sum256(contrib, red, tid);
        if (tid == 0) ws[OFF_OTX + ii] = contrib;

    } else if (bid < 704) {
        int q = bid - 640;
        small_sink<100, 100, true>(ws + OFF_CNN + (size_t)q * 10000, smem, red, tid,
                                   ws + OFF_OTNN + q);
    } else if (bid < 832) {
        int q = bid - 704;
        const float* base = (q < 64) ? (ws + OFF_CLN + (size_t)q * 5000)
                                     : (ws + OFF_CGN + (size_t)(q - 64) * 5000);
        float* outp = (q < 64) ? (ws + OFF_OTLN + q) : (ws + OFF_OTGN + (q - 64));
        small_sink<50, 100, false>(base, smem, red, tid, outp);
    } else {
        int q = bid - 832;
        small_sink<50, 50, true>(ws + OFF_CTT + (size_t)q * 2500, smem, red, tid,
                                 ws + OFF_OTTT + q);
    }
}

// ---------------- K3: final loss assembly ----------------
__global__ void assemble_kernel(const int* __restrict__ grade, const int* __restrict__ gneg,
                                const float* __restrict__ ws, float* __restrict__ out) {
    int i = threadIdx.x;
    float total = 0.f;
    if (i < 64) {
        float aa  = ws[OFF_OTAA + i];
        float nn  = ws[OFF_OTNN + i];
        float lnv = ws[OFF_OTLN + i];
        float gnv = ws[OFF_OTGN + i];
        int g  = grade[i];
        int gi = gneg[i];
        float tt9 = ws[OFF_OTTT + 9];
        float ttg = ws[OFF_OTTT + gi];
        float Slast = lnv - 0.5f * tt9 - 0.5f * nn;
        float Sgn   = gnv - 0.5f * ttg - 0.5f * nn;
        float Sv[10];
        #pragma unroll
        for (int k = 0; k < 10; k++)
            Sv[k] = ws[OFF_OTX + i * 10 + k] - 0.5f * aa - 0.5f * ws[OFF_OTTT + k];
        float pos = 0.f;
        #pragma unroll
        for (int k = 0; k < 10; k++) pos = (k == g) ? Sv[k] : pos;
        float hc = 0.f;
        #pragma unroll
        for (int k = 0; k < 10; k++)
            if (k != g) hc += fmaxf(pos - Sv[k] + MARGIN, 0.f);
        float hn = fmaxf(pos - Slast + MARGIN, 0.f);
        total = hc + hn + fabsf(Sgn - Slast);
    }
    #pragma unroll
    for (int off = 1; off < 64; off <<= 1) total += __shfl_xor(total, off);
    if (i == 0) out[0] = total * (1.0f / 64.0f);
}

extern "C" void kernel_launch(void* const* d_in, const int* in_sizes, int n_in,
                              void* d_out, int out_size, void* d_ws, size_t ws_size,
                              hipStream_t stream) {
    const float* anchor = (const float*)d_in[0];
    const int*   grade  = (const int*)d_in[2];
    const float* weight = (const float*)d_in[3];
    const float* neg    = (const float*)d_in[4];
    const int*   gneg   = (const int*)d_in[5];
    const float* t0     = (const float*)d_in[6];
    float* ws  = (float*)d_ws;
    float* out = (float*)d_out;

    sq_kernel      <<<5821, 256, 0, stream>>>(anchor, neg, t0, ws);
    cost128        <<<970, 256, 0, stream>>>(anchor, neg, t0, gneg, ws);
    aa_sink_reg    <<<64, 1024, 0, stream>>>(weight, ws);
    sink_rest      <<<842, 256, 0, stream>>>(weight, ws);
    assemble_kernel<<<1, 64, 0, stream>>>(grade, gneg, ws, out);
}

// Round 6
// 733.166 us; speedup vs baseline: 9.8568x; 1.0741x over previous
//
#include <hip/hip_runtime.h>

// Problem constants
#define NB   64
#define LA   256
#define DD   512
#define NCLS 10
#define NREF 50
#define NNEG 100
#define MARGIN 10.0f
#define NITER 27

#define LOG2E 1.44269504f
#define LN2   0.69314718f
#define LC50  (-3.9120230054f)   // log(1/50)
#define LC100 (-4.6051701860f)   // log(1/100)

// ---- workspace layout (float offsets) ----
// cross cost stored TRANSPOSED: [b][500][256] (t0-point major)
#define OFF_CX   ((size_t)0)
#define SZ_CX    ((size_t)64*500*256)
#define OFF_CAA  (OFF_CX + SZ_CX)
#define SZ_CAA   ((size_t)64*256*256)
#define OFF_CNN  (OFF_CAA + SZ_CAA)
#define SZ_CNN   ((size_t)64*100*100)
#define OFF_CLN  (OFF_CNN + SZ_CNN)
#define SZ_CLN   ((size_t)64*50*100)
#define OFF_CGN  (OFF_CLN + SZ_CLN)
#define SZ_CGN   ((size_t)64*50*100)
#define OFF_CTT  (OFF_CGN + SZ_CGN)
#define SZ_CTT   ((size_t)10*50*50)
#define OFF_SQA  (OFF_CTT + SZ_CTT)
#define OFF_SQN  (OFF_SQA + (size_t)64*256)
#define OFF_SQT  (OFF_SQN + (size_t)64*100)
#define OFF_OTX  (OFF_SQT + (size_t)500)
#define OFF_OTAA (OFF_OTX + (size_t)640)
#define OFF_OTNN (OFF_OTAA + (size_t)64)
#define OFF_OTLN (OFF_OTNN + (size_t)64)
#define OFF_OTGN (OFF_OTLN + (size_t)64)
#define OFF_OTTT (OFF_OTGN + (size_t)64)

__device__ __forceinline__ float eps_at(int it) {
    return (it < 12) ? ldexpf(8.0f, -it) : 0.0025f;
}

__device__ __forceinline__ float block_sum256(float v, float* red, int tid) {
    #pragma unroll
    for (int off = 1; off < 64; off <<= 1) v += __shfl_xor(v, off);
    if ((tid & 63) == 0) red[tid >> 6] = v;
    __syncthreads();
    return red[0] + red[1] + red[2] + red[3];
}

// ---------------- K0: 0.5 * squared norms ----------------
__global__ __launch_bounds__(256) void sq_kernel(const float* __restrict__ anchor,
                                                 const float* __restrict__ neg,
                                                 const float* __restrict__ t0,
                                                 float* __restrict__ ws) {
    int gw   = (blockIdx.x * 256 + threadIdx.x) >> 6;
    int lane = threadIdx.x & 63;
    const int nA = NB * LA, nN = NB * NNEG, nT = NCLS * NREF;
    if (gw >= nA + nN + nT) return;
    const float* row; float* outp;
    if (gw < nA)           { row = anchor + (size_t)gw * DD;          outp = ws + OFF_SQA + gw; }
    else if (gw < nA + nN) { int r = gw - nA;      row = neg + (size_t)r * DD; outp = ws + OFF_SQN + r; }
    else                   { int r = gw - nA - nN; row = t0  + (size_t)r * DD; outp = ws + OFF_SQT + r; }
    const float4* r4 = (const float4*)row;
    float4 u = r4[lane * 2], v = r4[lane * 2 + 1];
    float s = u.x*u.x + u.y*u.y + u.z*u.z + u.w*u.w
            + v.x*v.x + v.y*v.y + v.z*v.z + v.w*v.w;
    #pragma unroll
    for (int off = 1; off < 64; off <<= 1) s += __shfl_xor(s, off);
    if (lane == 0) *outp = 0.5f * s;
}

// ---------------- K1: cost matrices — 128x128 tile, 8x8 micro, K=16 ----------------
#define CTM 128
#define CTK 16
__global__ __launch_bounds__(256) void cost128(const float* __restrict__ anchor,
                                               const float* __restrict__ neg,
                                               const float* __restrict__ t0,
                                               const int* __restrict__ gneg,
                                               float* __restrict__ ws) {
    __shared__ __align__(16) float As[CTK][CTM];
    __shared__ __align__(16) float Bs[CTK][CTM];
    int bid = blockIdx.x, tid = threadIdx.x;
    const float *X, *Y, *sqx, *sqy;
    float* Cout; int N, M, ldc, r0, c0;
    bool tr = false;
    if (bid < 512) {
        int b = bid >> 3, t = bid & 7;
        r0 = (t >> 2) * 128; c0 = (t & 3) * 128;
        X = anchor + (size_t)b * LA * DD; Y = t0; N = LA; M = 500; ldc = 500;
        Cout = ws + OFF_CX + (size_t)b * 500 * 256;
        sqx = ws + OFF_SQA + b * LA; sqy = ws + OFF_SQT;
        tr = true;
    } else if (bid < 768) {
        int b2 = bid - 512; int b = b2 >> 2, t = b2 & 3;
        r0 = (t >> 1) * 128; c0 = (t & 1) * 128;
        X = Y = anchor + (size_t)b * LA * DD; N = M = LA; ldc = LA;
        Cout = ws + OFF_CAA + (size_t)b * LA * LA;
        sqx = sqy = ws + OFF_SQA + b * LA;
    } else if (bid < 832) {
        int b = bid - 768; r0 = 0; c0 = 0;
        X = Y = neg + (size_t)b * NNEG * DD; N = M = NNEG; ldc = NNEG;
        Cout = ws + OFF_CNN + (size_t)b * NNEG * NNEG;
        sqx = sqy = ws + OFF_SQN + b * NNEG;
    } else if (bid < 896) {
        int b = bid - 832; r0 = 0; c0 = 0;
        X = t0 + (size_t)9 * NREF * DD; Y = neg + (size_t)b * NNEG * DD;
        N = NREF; M = NNEG; ldc = NNEG;
        Cout = ws + OFF_CLN + (size_t)b * NREF * NNEG;
        sqx = ws + OFF_SQT + 9 * NREF; sqy = ws + OFF_SQN + b * NNEG;
    } else if (bid < 960) {
        int b = bid - 896; r0 = 0; c0 = 0;
        int gc = gneg[b];
        X = t0 + (size_t)gc * NREF * DD; Y = neg + (size_t)b * NNEG * DD;
        N = NREF; M = NNEG; ldc = NNEG;
        Cout = ws + OFF_CGN + (size_t)b * NREF * NNEG;
        sqx = ws + OFF_SQT + gc * NREF; sqy = ws + OFF_SQN + b * NNEG;
    } else {
        int c = bid - 960; r0 = 0; c0 = 0;
        X = Y = t0 + (size_t)c * NREF * DD; N = M = NREF; ldc = NREF;
        Cout = ws + OFF_CTT + (size_t)c * NREF * NREF;
        sqx = sqy = ws + OFF_SQT + c * NREF;
    }
    int row = tid & 127, kq = tid >> 7;
    int tx = tid & 15, ty = tid >> 4;
    bool xok = (r0 + row) < N, yok = (c0 + row) < M;
    const float* xrow = X + (size_t)(r0 + row) * DD + kq * 8;
    const float* yrow = Y + (size_t)(c0 + row) * DD + kq * 8;
    float acc[8][8];
    #pragma unroll
    for (int a = 0; a < 8; a++)
        #pragma unroll
        for (int b = 0; b < 8; b++) acc[a][b] = 0.f;
    for (int k0 = 0; k0 < DD; k0 += CTK) {
        float4 xa0 = xok ? *(const float4*)(xrow + k0)     : make_float4(0,0,0,0);
        float4 xa1 = xok ? *(const float4*)(xrow + k0 + 4) : make_float4(0,0,0,0);
        float4 ya0 = yok ? *(const float4*)(yrow + k0)     : make_float4(0,0,0,0);
        float4 ya1 = yok ? *(const float4*)(yrow + k0 + 4) : make_float4(0,0,0,0);
        __syncthreads();
        int kb = kq * 8;
        As[kb+0][row]=xa0.x; As[kb+1][row]=xa0.y; As[kb+2][row]=xa0.z; As[kb+3][row]=xa0.w;
        As[kb+4][row]=xa1.x; As[kb+5][row]=xa1.y; As[kb+6][row]=xa1.z; As[kb+7][row]=xa1.w;
        Bs[kb+0][row]=ya0.x; Bs[kb+1][row]=ya0.y; Bs[kb+2][row]=ya0.z; Bs[kb+3][row]=ya0.w;
        Bs[kb+4][row]=ya1.x; Bs[kb+5][row]=ya1.y; Bs[kb+6][row]=ya1.z; Bs[kb+7][row]=ya1.w;
        __syncthreads();
        #pragma unroll
        for (int k = 0; k < CTK; k++) {
            float4 a0 = *(const float4*)&As[k][ty << 3];
            float4 a1 = *(const float4*)&As[k][(ty << 3) + 4];
            float4 b0 = *(const float4*)&Bs[k][tx << 3];
            float4 b1 = *(const float4*)&Bs[k][(tx << 3) + 4];
            float av[8] = {a0.x,a0.y,a0.z,a0.w,a1.x,a1.y,a1.z,a1.w};
            float bv[8] = {b0.x,b0.y,b0.z,b0.w,b1.x,b1.y,b1.z,b1.w};
            #pragma unroll
            for (int a = 0; a < 8; a++)
                #pragma unroll
                for (int b = 0; b < 8; b++)
                    acc[a][b] = fmaf(av[a], bv[b], acc[a][b]);
        }
    }
    #pragma unroll
    for (int a = 0; a < 8; a++) {
        int n = r0 + (ty << 3) + a;
        if (n < N) {
            float sx = sqx[n];
            #pragma unroll
            for (int b = 0; b < 8; b++) {
                int m = c0 + (tx << 3) + b;
                if (m < M) {
                    float v = sx + sqy[m] - acc[a][b];
                    if (tr) Cout[(size_t)m * 256 + n] = v;
                    else    Cout[(size_t)n * ldc + m] = v;
                }
            }
        }
    }
}

// ---------------- K2a: aa Sinkhorn, C register-resident, float4 LDS reads ----------------
__global__ __launch_bounds__(1024, 1) void aa_sink_reg(const float* __restrict__ weight,
                                                       float* __restrict__ ws) {
    __shared__ __align__(16) float ahS[256];
    __shared__ float pm[4][256];
    __shared__ float ps[4][256];
    __shared__ float red[16];
    int i = blockIdx.x, tid = threadIdx.x;
    int w = tid >> 6, lane = tid & 63;
    int q = w >> 2;
    int c = ((w & 3) << 6) | lane;
    const float* Cg = ws + OFF_CAA + ((size_t)i << 16);
    float Creg[64];
    #pragma unroll
    for (int k = 0; k < 64; ++k)
        Creg[k] = Cg[(size_t)((q << 6) + k) * 256 + c];
    float wgt = weight[(size_t)i * LA + c];
    float la = (wgt > 0.f) ? __logf(fmaxf(wgt, 1e-30f)) : -1e9f;
    float h = 0.f, fs = 0.f;
    if (q == 0) ahS[c] = 8.0f * la;
    __syncthreads();
    int r4 = q << 4;
    const float4* ah4 = (const float4*)ahS;
    for (int app = 0; app < 54; ++app) {
        float eps = eps_at(app >> 1);
        float m0 = -3.4e38f, m1 = -3.4e38f, m2 = -3.4e38f, m3 = -3.4e38f;
        #pragma unroll
        for (int k = 0; k < 16; ++k) {
            float4 av = ah4[r4 + k];
            m0 = fmaxf(m0, av.x - Creg[4*k+0]);
            m1 = fmaxf(m1, av.y - Creg[4*k+1]);
            m2 = fmaxf(m2, av.z - Creg[4*k+2]);
            m3 = fmaxf(m3, av.w - Creg[4*k+3]);
        }
        pm[q][c] = fmaxf(fmaxf(m0, m1), fmaxf(m2, m3));
        __syncthreads();
        float m = fmaxf(fmaxf(pm[0][c], pm[1][c]), fmaxf(pm[2][c], pm[3][c]));
        float ie2 = (1.0f / eps) * LOG2E;
        float s0 = 0.f, s1 = 0.f, s2 = 0.f, s3 = 0.f;
        #pragma unroll
        for (int k = 0; k < 16; ++k) {
            float4 av = ah4[r4 + k];
            s0 += exp2f((av.x - Creg[4*k+0] - m) * ie2);
            s1 += exp2f((av.y - Creg[4*k+1] - m) * ie2);
            s2 += exp2f((av.z - Creg[4*k+2] - m) * ie2);
            s3 += exp2f((av.w - Creg[4*k+3] - m) * ie2);
        }
        ps[q][c] = (s0 + s1) + (s2 + s3);
        __syncthreads();
        float s = (ps[0][c] + ps[1][c]) + (ps[2][c] + ps[3][c]);
        h = -fmaf(eps * LN2, __log2f(s), m);
        if (app == 52) fs = h;
        if (q == 0) {
            float epsn = eps_at((app + 1) >> 1);
            ahS[c] = fmaf(epsn, la, h);
        }
        __syncthreads();
    }
    float contrib = (q == 0) ? wgt * (fs + h) : 0.f;
    #pragma unroll
    for (int off = 1; off < 64; off <<= 1) contrib += __shfl_xor(contrib, off);
    if (lane == 0) red[w] = contrib;
    __syncthreads();
    if (tid == 0) {
        float s = 0.f;
        #pragma unroll
        for (int k = 0; k < 16; ++k) s += red[k];
        ws[OFF_OTAA + i] = s;
    }
}

// ---------------- K2b: cross + nn + ln + gn + tt (all register-resident C) ----------------
__global__ __launch_bounds__(256, 3) void sink_rest(const float* __restrict__ weight,
                                                    float* __restrict__ ws) {
    __shared__ __align__(16) float smem[13324];
    float* red = smem + 13320;
    int bid = blockIdx.x, tid = threadIdx.x;

    if (bid < 640) {
        // ---- cross (256x50): C^T [50][260] LDS; f reg-resident; g 16-lane groups ----
        int ii = bid;
        int i = ii / 10, c = ii - i * 10;
        float* CsT = smem;                 // [50][260]
        float* agS = smem + 13000;         // [256] = eps*la + f
        float* gSp = smem + 13260;         // [52] raw g, padded
        const float* Cgbase = ws + OFF_CX + (size_t)i * (500 * 256) + (size_t)c * (50 * 256);
        for (int e = tid; e < 3200; e += 256) {
            int r = e >> 6, n4 = (e & 63) << 2;
            *(float4*)&CsT[r * 260 + n4] = *(const float4*)&Cgbase[(size_t)e << 2];
        }
        float w = weight[(size_t)i * LA + tid];
        float la_r = (w > 0.f) ? __logf(fmaxf(w, 1e-30f)) : -1e9f;
        if (tid < 52) gSp[tid] = (tid < 50) ? 0.f : -1.0e30f;
        __syncthreads();
        float Creg[52];
        #pragma unroll
        for (int r = 0; r < 52; ++r) Creg[r] = (r < 50) ? CsT[r * 260 + tid] : 3.0e30f;
        int grp = tid >> 4, j = tid & 15;
        for (int it = 0; it < NITER; ++it) {
            float eps = eps_at(it), ie2 = (1.0f / eps) * LOG2E;
            // f-update: reg two-pass over 52 (padded), gSp via float4
            {
                const float4* g4 = (const float4*)gSp;
                float m0=-3.4e38f, m1=-3.4e38f, m2=-3.4e38f, m3=-3.4e38f;
                #pragma unroll
                for (int k = 0; k < 13; ++k) {
                    float4 gv = g4[k];
                    m0 = fmaxf(m0, gv.x - Creg[4*k+0]);
                    m1 = fmaxf(m1, gv.y - Creg[4*k+1]);
                    m2 = fmaxf(m2, gv.z - Creg[4*k+2]);
                    m3 = fmaxf(m3, gv.w - Creg[4*k+3]);
                }
                float m = fmaxf(fmaxf(m0, m1), fmaxf(m2, m3));
                float s0=0.f, s1=0.f, s2=0.f, s3=0.f;
                #pragma unroll
                for (int k = 0; k < 13; ++k) {
                    float4 gv = g4[k];
                    s0 += exp2f((gv.x - Creg[4*k+0] - m) * ie2);
                    s1 += exp2f((gv.y - Creg[4*k+1] - m) * ie2);
                    s2 += exp2f((gv.z - Creg[4*k+2] - m) * ie2);
                    s3 += exp2f((gv.w - Creg[4*k+3] - m) * ie2);
                }
                float L = fmaf(eps * LN2, __log2f((s0+s1)+(s2+s3)), m);
                float f = -fmaf(eps, LC50, L);
                agS[tid] = fmaf(eps, la_r, f);
            }
            __syncthreads();
            // g-update: 16-lane groups, float4 reads of agS and C rows
            float4 agr[4];
            #pragma unroll
            for (int q = 0; q < 4; ++q)
                agr[q] = *(const float4*)&agS[(j << 2) + (q << 6)];
            for (int o = grp; o < 50; o += 16) {
                const float* Cr = &CsT[o * 260];
                float u[16];
                #pragma unroll
                for (int q = 0; q < 4; ++q) {
                    float4 cv = *(const float4*)&Cr[(j << 2) + (q << 6)];
                    u[4*q+0] = agr[q].x - cv.x;
                    u[4*q+1] = agr[q].y - cv.y;
                    u[4*q+2] = agr[q].z - cv.z;
                    u[4*q+3] = agr[q].w - cv.w;
                }
                float a0 = fmaxf(fmaxf(u[0], u[4]),  fmaxf(u[8],  u[12]));
                float a1 = fmaxf(fmaxf(u[1], u[5]),  fmaxf(u[9],  u[13]));
                float a2 = fmaxf(fmaxf(u[2], u[6]),  fmaxf(u[10], u[14]));
                float a3 = fmaxf(fmaxf(u[3], u[7]),  fmaxf(u[11], u[15]));
                float m = fmaxf(fmaxf(a0, a1), fmaxf(a2, a3));
                #pragma unroll
                for (int off = 1; off < 16; off <<= 1) m = fmaxf(m, __shfl_xor(m, off));
                float s0=0.f, s1=0.f, s2=0.f, s3=0.f;
                #pragma unroll
                for (int k = 0; k < 16; ++k) {
                    float e = exp2f((u[k] - m) * ie2);
                    if ((k & 3) == 0) s0 += e;
                    else if ((k & 3) == 1) s1 += e;
                    else if ((k & 3) == 2) s2 += e;
                    else s3 += e;
                }
                float s = (s0 + s1) + (s2 + s3);
                #pragma unroll
                for (int off = 1; off < 16; off <<= 1) s += __shfl_xor(s, off);
                if (j == 0) gSp[o] = -fmaf(eps * LN2, __log2f(s), m);
            }
            __syncthreads();
        }
        float f_t = agS[tid] - 0.0025f * la_r;
        float contrib = w * f_t + (tid < 50 ? 0.02f * gSp[tid] : 0.f);
        contrib = block_sum256(contrib, red, tid);
        if (tid == 0) ws[OFF_OTX + ii] = contrib;

    } else if (bid < 704) {
        // ---- nn (100x100 symmetric): C reg-resident, thread (q,c), 52 rows each ----
        int inst = bid - 640;
        const float* Cg = ws + OFF_CNN + (size_t)inst * 10000;
        float* ahS = smem;            // [104] padded
        float* pmS = smem + 104;      // [2][100]
        float* psS = smem + 304;      // [2][100]
        bool act = tid < 200;
        int q = tid / 100, c = tid - 100 * q;
        float Creg[52];
        if (act) {
            #pragma unroll
            for (int k = 0; k < 52; ++k) {
                int r = q * 52 + k;
                Creg[k] = (r < 100) ? Cg[(size_t)r * 100 + c] : 3.0e30f;
            }
        }
        if (tid < 100) ahS[tid] = 8.0f * LC100;
        if (tid >= 100 && tid < 104) ahS[tid] = -1.0e30f;
        __syncthreads();
        float h = 0.f, fs = 0.f, m = 0.f;
        for (int app = 0; app < 54; ++app) {
            float eps = eps_at(app >> 1);
            if (act) {
                const float4* ah4 = (const float4*)(ahS + q * 52);
                float m0=-3.4e38f, m1=-3.4e38f, m2=-3.4e38f, m3=-3.4e38f;
                #pragma unroll
                for (int k = 0; k < 13; ++k) {
                    float4 av = ah4[k];
                    m0 = fmaxf(m0, av.x - Creg[4*k+0]);
                    m1 = fmaxf(m1, av.y - Creg[4*k+1]);
                    m2 = fmaxf(m2, av.z - Creg[4*k+2]);
                    m3 = fmaxf(m3, av.w - Creg[4*k+3]);
                }
                pmS[q * 100 + c] = fmaxf(fmaxf(m0, m1), fmaxf(m2, m3));
            }
            __syncthreads();
            if (act) {
                m = fmaxf(pmS[c], pmS[100 + c]);
                float ie2 = (1.0f / eps) * LOG2E;
                const float4* ah4 = (const float4*)(ahS + q * 52);
                float s0=0.f, s1=0.f, s2=0.f, s3=0.f;
                #pragma unroll
                for (int k = 0; k < 13; ++k) {
                    float4 av = ah4[k];
                    s0 += exp2f((av.x - Creg[4*k+0] - m) * ie2);
                    s1 += exp2f((av.y - Creg[4*k+1] - m) * ie2);
                    s2 += exp2f((av.z - Creg[4*k+2] - m) * ie2);
                    s3 += exp2f((av.w - Creg[4*k+3] - m) * ie2);
                }
                psS[q * 100 + c] = (s0 + s1) + (s2 + s3);
            }
            __syncthreads();
            if (act) {
                float s = psS[c] + psS[100 + c];
                h = -fmaf(eps * LN2, __log2f(s), m);
                if (app == 52) fs = h;
                if (q == 0) {
                    float epsn = eps_at((app + 1) >> 1);
                    ahS[c] = fmaf(epsn, LC100, h);
                }
            }
            __syncthreads();
        }
        float contrib = (act && q == 0) ? 0.01f * (fs + h) : 0.f;
        contrib = block_sum256(contrib, red, tid);
        if (tid == 0) ws[OFF_OTNN + inst] = contrib;

    } else if (bid < 832) {
        // ---- ln/gn (50x100 asymmetric): dual-orientation reg-resident C ----
        int q2 = bid - 704;
        const float* Cg = (q2 < 64) ? ws + OFF_CLN + (size_t)q2 * 5000
                                    : ws + OFF_CGN + (size_t)(q2 - 64) * 5000;
        float* outp = (q2 < 64) ? ws + OFF_OTLN + q2 : ws + OFF_OTGN + (q2 - 64);
        float* gSp = smem;            // [100] = eps*lb + g
        float* fSp = smem + 100;      // [56]  = eps*la + f, padded
        float* pmf = smem + 156;      // [5][50]
        float* psf = smem + 406;      // [5][50]
        float* pmg = smem + 656;      // [2][100]
        float* psg = smem + 856;      // [2][100]
        bool actf = tid < 250; int rf = tid / 5, c5 = tid - 5 * rf;
        bool actg = tid < 200; int cg = tid >> 1, hg = tid & 1;
        float Cf[20], Cgr[28];
        if (actf) {
            #pragma unroll
            for (int k = 0; k < 20; ++k) Cf[k] = Cg[(size_t)rf * 100 + c5 * 20 + k];
        }
        if (actg) {
            #pragma unroll
            for (int k = 0; k < 28; ++k) {
                int r = hg * 28 + k;
                Cgr[k] = (r < 50) ? Cg[(size_t)r * 100 + cg] : 3.0e30f;
            }
        }
        if (tid < 100) gSp[tid] = 8.0f * LC100;
        if (tid < 6) fSp[50 + tid] = -1.0e30f;
        __syncthreads();
        float fr = 0.f, gr = 0.f, mf = 0.f, mg = 0.f;
        for (int it = 0; it < NITER; ++it) {
            float eps = eps_at(it), ie2 = (1.0f / eps) * LOG2E;
            // f-update (50 outputs, reduce over 100)
            if (actf) {
                const float4* g4 = (const float4*)(gSp + c5 * 20);
                float m0=-3.4e38f, m1=-3.4e38f, m2=-3.4e38f, m3=-3.4e38f;
                #pragma unroll
                for (int k = 0; k < 5; ++k) {
                    float4 gv = g4[k];
                    m0 = fmaxf(m0, gv.x - Cf[4*k+0]);
                    m1 = fmaxf(m1, gv.y - Cf[4*k+1]);
                    m2 = fmaxf(m2, gv.z - Cf[4*k+2]);
                    m3 = fmaxf(m3, gv.w - Cf[4*k+3]);
                }
                pmf[c5 * 50 + rf] = fmaxf(fmaxf(m0, m1), fmaxf(m2, m3));
            }
            __syncthreads();
            if (actf) {
                mf = fmaxf(fmaxf(pmf[rf], pmf[50 + rf]),
                     fmaxf(fmaxf(pmf[100 + rf], pmf[150 + rf]), pmf[200 + rf]));
                const float4* g4 = (const float4*)(gSp + c5 * 20);
                float s0=0.f, s1=0.f, s2=0.f, s3=0.f;
                #pragma unroll
                for (int k = 0; k < 5; ++k) {
                    float4 gv = g4[k];
                    s0 += exp2f((gv.x - Cf[4*k+0] - mf) * ie2);
                    s1 += exp2f((gv.y - Cf[4*k+1] - mf) * ie2);
                    s2 += exp2f((gv.z - Cf[4*k+2] - mf) * ie2);
                    s3 += exp2f((gv.w - Cf[4*k+3] - mf) * ie2);
                }
                psf[c5 * 50 + rf] = (s0 + s1) + (s2 + s3);
            }
            __syncthreads();
            if (actf) {
                float s = psf[rf] + psf[50 + rf] + psf[100 + rf] + psf[150 + rf] + psf[200 + rf];
                fr = -fmaf(eps * LN2, __log2f(s), mf);
                if (c5 == 0) fSp[rf] = fmaf(eps, LC50, fr);
            }
            __syncthreads();
            // g-update (100 outputs, reduce over 50)
            if (actg) {
                const float4* f4 = (const float4*)(fSp + hg * 28);
                float m0=-3.4e38f, m1=-3.4e38f, m2=-3.4e38f, m3=-3.4e38f;
                #pragma unroll
                for (int k = 0; k < 7; ++k) {
                    float4 fv = f4[k];
                    m0 = fmaxf(m0, fv.x - Cgr[4*k+0]);
                    m1 = fmaxf(m1, fv.y - Cgr[4*k+1]);
                    m2 = fmaxf(m2, fv.z - Cgr[4*k+2]);
                    m3 = fmaxf(m3, fv.w - Cgr[4*k+3]);
                }
                pmg[hg * 100 + cg] = fmaxf(fmaxf(m0, m1), fmaxf(m2, m3));
            }
            __syncthreads();
            if (actg) {
                mg = fmaxf(pmg[cg], pmg[100 + cg]);
                const float4* f4 = (const float4*)(fSp + hg * 28);
                float s0=0.f, s1=0.f, s2=0.f, s3=0.f;
                #pragma unroll
                for (int k = 0; k < 7; ++k) {
                    float4 fv = f4[k];
                    s0 += exp2f((fv.x - Cgr[4*k+0] - mg) * ie2);
                    s1 += exp2f((fv.y - Cgr[4*k+1] - mg) * ie2);
                    s2 += exp2f((fv.z - Cgr[4*k+2] - mg) * ie2);
                    s3 += exp2f((fv.w - Cgr[4*k+3] - mg) * ie2);
                }
                psg[hg * 100 + cg] = (s0 + s1) + (s2 + s3);
            }
            __syncthreads();
            if (actg) {
                float s = psg[cg] + psg[100 + cg];
                gr = -fmaf(eps * LN2, __log2f(s), mg);
                if (hg == 0) {
                    float epsn = eps_at(it + 1);
                    gSp[cg] = fmaf(epsn, LC100, gr);
                }
            }
            __syncthreads();
        }
        float contrib = 0.f;
        if (actf && c5 == 0) contrib += 0.02f * fr;
        if (actg && hg == 0) contrib += 0.01f * gr;
        contrib = block_sum256(contrib, red, tid);
        if (tid == 0) *outp = contrib;

    } else {
        // ---- tt (50x50 symmetric): full column in registers ----
        int inst = bid - 832;
        const float* Cg = ws + OFF_CTT + (size_t)inst * 2500;
        float* ahS = smem;            // [52] padded
        bool act = tid < 50;
        float Creg[52];
        if (act) {
            #pragma unroll
            for (int k = 0; k < 52; ++k)
                Creg[k] = (k < 50) ? Cg[(size_t)k * 50 + tid] : 3.0e30f;
        }
        if (tid < 50) ahS[tid] = 8.0f * LC50;
        if (tid >= 50 && tid < 52) ahS[tid] = -1.0e30f;
        __syncthreads();
        float h = 0.f, fs = 0.f;
        const float4* ah4 = (const float4*)ahS;
        for (int app = 0; app < 54; ++app) {
            float eps = eps_at(app >> 1);
            if (act) {
                float m0=-3.4e38f, m1=-3.4e38f, m2=-3.4e38f, m3=-3.4e38f;
                #pragma unroll
                for (int k = 0; k < 13; ++k) {
                    float4 av = ah4[k];
                    m0 = fmaxf(m0, av.x - Creg[4*k+0]);
                    m1 = fmaxf(m1, av.y - Creg[4*k+1]);
                    m2 = fmaxf(m2, av.z - Creg[4*k+2]);
                    m3 = fmaxf(m3, av.w - Creg[4*k+3]);
                }
                float m = fmaxf(fmaxf(m0, m1), fmaxf(m2, m3));
                float ie2 = (1.0f / eps) * LOG2E;
                float s0=0.f, s1=0.f, s2=0.f, s3=0.f;
                #pragma unroll
                for (int k = 0; k < 13; ++k) {
                    float4 av = ah4[k];
                    s0 += exp2f((av.x - Creg[4*k+0] - m) * ie2);
                    s1 += exp2f((av.y - Creg[4*k+1] - m) * ie2);
                    s2 += exp2f((av.z - Creg[4*k+2] - m) * ie2);
                    s3 += exp2f((av.w - Creg[4*k+3] - m) * ie2);
                }
                h = -fmaf(eps * LN2, __log2f((s0+s1)+(s2+s3)), m);
                if (app == 52) fs = h;
            }
            __syncthreads();
            if (act) {
                float epsn = eps_at((app + 1) >> 1);
                ahS[tid] = fmaf(epsn, LC50, h);
            }
            __syncthreads();
        }
        float contrib = act ? 0.02f * (fs + h) : 0.f;
        contrib = block_sum256(contrib, red, tid);
        if (tid == 0) ws[OFF_OTTT + inst] = contrib;
    }
}

// ---------------- K3: final loss assembly ----------------
__global__ void assemble_kernel(const int* __restrict__ grade, const int* __restrict__ gneg,
                                const float* __restrict__ ws, float* __restrict__ out) {
    int i = threadIdx.x;
    float total = 0.f;
    if (i < 64) {
        float aa  = ws[OFF_OTAA + i];
        float nn  = ws[OFF_OTNN + i];
        float lnv = ws[OFF_OTLN + i];
        float gnv = ws[OFF_OTGN + i];
        int g  = grade[i];
        int gi = gneg[i];
        float tt9 = ws[OFF_OTTT + 9];
        float ttg = ws[OFF_OTTT + gi];
        float Slast = lnv - 0.5f * tt9 - 0.5f * nn;
        float Sgn   = gnv - 0.5f * ttg - 0.5f * nn;
        float Sv[10];
        #pragma unroll
        for (int k = 0; k < 10; k++)
            Sv[k] = ws[OFF_OTX + i * 10 + k] - 0.5f * aa - 0.5f * ws[OFF_OTTT + k];
        float pos = 0.f;
        #pragma unroll
        for (int k = 0; k < 10; k++) pos = (k == g) ? Sv[k] : pos;
        float hc = 0.f;
        #pragma unroll
        for (int k = 0; k < 10; k++)
            if (k != g) hc += fmaxf(pos - Sv[k] + MARGIN, 0.f);
        float hn = fmaxf(pos - Slast + MARGIN, 0.f);
        total = hc + hn + fabsf(Sgn - Slast);
    }
    #pragma unroll
    for (int off = 1; off < 64; off <<= 1) total += __shfl_xor(total, off);
    if (i == 0) out[0] = total * (1.0f / 64.0f);
}

extern "C" void kernel_launch(void* const* d_in, const int* in_sizes, int n_in,
                              void* d_out, int out_size, void* d_ws, size_t ws_size,
                              hipStream_t stream) {
    const float* anchor = (const float*)d_in[0];
    const int*   grade  = (const int*)d_in[2];
    const float* weight = (const float*)d_in[3];
    const float* neg    = (const float*)d_in[4];
    const int*   gneg   = (const int*)d_in[5];
    const float* t0     = (const float*)d_in[6];
    float* ws  = (float*)d_ws;
    float* out = (float*)d_out;

    sq_kernel      <<<5821, 256, 0, stream>>>(anchor, neg, t0, ws);
    cost128        <<<970, 256, 0, stream>>>(anchor, neg, t0, gneg, ws);
    aa_sink_reg    <<<64, 1024, 0, stream>>>(weight, ws);
    sink_rest      <<<842, 256, 0, stream>>>(weight, ws);
    assemble_kernel<<<1, 64, 0, stream>>>(grade, gneg, ws, out);
}